// Round 1
// baseline (2593.560 us; speedup 1.0000x reference)
//
#include <hip/hip_runtime.h>
#include <math.h>

#define TB 256

// ---------------- channel-slice copy (for concat) ----------------
__global__ __launch_bounds__(256) void copych_k(
    const float* __restrict__ src, float* __restrict__ dst,
    int N, int C, int HW, int ocoff, int ocstride) {
  int idx = blockIdx.x * TB + threadIdx.x;
  int total = N * C * HW;
  if (idx >= total) return;
  int i = idx % HW;
  int t = idx / HW;
  int c = t % C;
  int n = t / C;
  dst[((size_t)n * ocstride + ocoff + c) * HW + i] = src[idx];
}

// ---------------- maxpool 3x3 stride2 pad1 ----------------
__global__ __launch_bounds__(256) void maxpool3s2_k(
    const float* __restrict__ in, float* __restrict__ out,
    int NC, int H, int W, int Ho, int Wo) {
  int idx = blockIdx.x * TB + threadIdx.x;
  int total = NC * Ho * Wo;
  if (idx >= total) return;
  int wo = idx % Wo;
  int t = idx / Wo;
  int ho = t % Ho;
  int nc = t / Ho;
  const float* src = in + (size_t)nc * H * W;
  int y0 = 2 * ho - 1, x0 = 2 * wo - 1;
  float m = -INFINITY;
  for (int dy = 0; dy < 3; ++dy) {
    int y = y0 + dy;
    if (y < 0 || y >= H) continue;
    for (int dx = 0; dx < 3; ++dx) {
      int x = x0 + dx;
      if (x < 0 || x >= W) continue;
      m = fmaxf(m, src[(size_t)y * W + x]);
    }
  }
  out[idx] = m;
}

// ---------------- bilinear x2 upsample (jax.image.resize, half-pixel) ----------------
__global__ __launch_bounds__(256) void up2_k(
    const float* __restrict__ in, float* __restrict__ out,
    int N, int C, int H, int W, int ocoff, int ocstride) {
  int Ho = 2 * H, Wo = 2 * W;
  int total = N * C * Ho * Wo;
  int idx = blockIdx.x * TB + threadIdx.x;
  if (idx >= total) return;
  int xo = idx % Wo;
  int t = idx / Wo;
  int yo = t % Ho;
  t /= Ho;
  int c = t % C;
  int n = t / C;
  // sample_f = (o+0.5)/2 - 0.5 ; edge renormalization == clamp-replicate
  float sy = 0.5f * yo - 0.25f;
  float sx = 0.5f * xo - 0.25f;
  float y0f = floorf(sy), x0f = floorf(sx);
  float wy = sy - y0f, wx = sx - x0f;
  int y0 = (int)y0f, x0 = (int)x0f;
  int y0c = min(max(y0, 0), H - 1), y1c = min(max(y0 + 1, 0), H - 1);
  int x0c = min(max(x0, 0), W - 1), x1c = min(max(x0 + 1, 0), W - 1);
  const float* s = in + ((size_t)n * C + c) * H * W;
  float v = (1.f - wy) * ((1.f - wx) * s[(size_t)y0c * W + x0c] + wx * s[(size_t)y0c * W + x1c]) +
            wy * ((1.f - wx) * s[(size_t)y1c * W + x0c] + wx * s[(size_t)y1c * W + x1c]);
  out[(((size_t)n * ocstride + ocoff + c) * Ho + yo) * Wo + xo] = v;
}

// ---------------- 3x3 conv, stride1 pad1, LDS-tiled ----------------
// block 16x16 spatial tile; each thread accumulates all COUT outputs.
template <int COUT>
__global__ __launch_bounds__(256) void conv3x3_k(
    const float* __restrict__ in, const float* __restrict__ wgt,
    const float* __restrict__ bias, float* __restrict__ out,
    int N, int Cin, int H, int W, int relu, int ocoff, int ocstride) {
  extern __shared__ float tile[];  // Cin * 18 * 18
  int n = blockIdx.z;
  int bx = blockIdx.x * 16, by = blockIdx.y * 16;
  int tx = threadIdx.x, ty = threadIdx.y;
  int tid = ty * 16 + tx;
  int total = Cin * 324;
  const float* inN = in + (size_t)n * Cin * H * W;
  for (int idx = tid; idx < total; idx += 256) {
    int c = idx / 324;
    int rem = idx - c * 324;
    int ly = rem / 18;
    int lx = rem - ly * 18;
    int gy = by + ly - 1, gx = bx + lx - 1;
    float v = 0.f;
    if (gy >= 0 && gy < H && gx >= 0 && gx < W)
      v = inN[((size_t)c * H + gy) * W + gx];
    tile[idx] = v;
  }
  __syncthreads();
  float acc[COUT];
#pragma unroll
  for (int o = 0; o < COUT; ++o) acc[o] = bias ? bias[o] : 0.f;
  for (int c = 0; c < Cin; ++c) {
    const float* tc = tile + c * 324;
    const float* wc = wgt + (size_t)c * 9;
#pragma unroll
    for (int k = 0; k < 9; ++k) {
      int ky = k / 3, kx = k - (k / 3) * 3;
      float v = tc[(ty + ky) * 18 + (tx + kx)];
#pragma unroll
      for (int o = 0; o < COUT; ++o)
        acc[o] = fmaf(v, wc[(size_t)o * Cin * 9 + k], acc[o]);
    }
  }
  int h = by + ty, w = bx + tx;
  if (h < H && w < W) {
#pragma unroll
    for (int o = 0; o < COUT; ++o) {
      float r = acc[o];
      if (relu) r = fmaxf(r, 0.f);
      out[(((size_t)n * ocstride + ocoff + o) * H + h) * W + w] = r;
    }
  }
}

// ---------------- deformable 3x3 conv (mmcv, no modulation/bias) ----------------
template <int COUT>
__global__ __launch_bounds__(256) void deform3x3_k(
    const float* __restrict__ in, const float* __restrict__ off,
    const float* __restrict__ wgt, float* __restrict__ out,
    int N, int Cin, int H, int W, int dg, int relu, int ocoff, int ocstride) {
  int n = blockIdx.z;
  int h = blockIdx.y * 16 + threadIdx.y;
  int w = blockIdx.x * 16 + threadIdx.x;
  if (h >= H || w >= W) return;
  int Cg = Cin / dg;
  int offC = dg * 18;
  float acc[COUT];
#pragma unroll
  for (int o = 0; o < COUT; ++o) acc[o] = 0.f;
  const float* inN = in + (size_t)n * Cin * H * W;
  const float* offN = off + (size_t)n * offC * H * W;
  for (int g = 0; g < dg; ++g) {
    for (int k = 0; k < 9; ++k) {
      int ky = k / 3 - 1, kx = k % 3 - 1;
      float oy = offN[((size_t)((g * 9 + k) * 2 + 0) * H + h) * W + w];
      float ox = offN[((size_t)((g * 9 + k) * 2 + 1) * H + h) * W + w];
      float py = (float)(h + ky) + oy;
      float px = (float)(w + kx) + ox;
      float y0f = floorf(py), x0f = floorf(px);
      float wy = py - y0f, wx = px - x0f;
      int y0 = (int)y0f, x0 = (int)x0f;
      bool vy0 = (y0 >= 0) && (y0 < H);
      bool vy1 = (y0 + 1 >= 0) && (y0 + 1 < H);
      bool vx0 = (x0 >= 0) && (x0 < W);
      bool vx1 = (x0 + 1 >= 0) && (x0 + 1 < W);
      int y0c = min(max(y0, 0), H - 1), y1c = min(max(y0 + 1, 0), H - 1);
      int x0c = min(max(x0, 0), W - 1), x1c = min(max(x0 + 1, 0), W - 1);
      float w00 = (1.f - wy) * (1.f - wx), w01 = (1.f - wy) * wx;
      float w10 = wy * (1.f - wx), w11 = wy * wx;
      for (int ci = 0; ci < Cg; ++ci) {
        int c = g * Cg + ci;
        const float* s = inN + (size_t)c * H * W;
        float v00 = (vy0 && vx0) ? s[(size_t)y0c * W + x0c] : 0.f;
        float v01 = (vy0 && vx1) ? s[(size_t)y0c * W + x1c] : 0.f;
        float v10 = (vy1 && vx0) ? s[(size_t)y1c * W + x0c] : 0.f;
        float v11 = (vy1 && vx1) ? s[(size_t)y1c * W + x1c] : 0.f;
        float v = w00 * v00 + w01 * v01 + w10 * v10 + w11 * v11;
#pragma unroll
        for (int o = 0; o < COUT; ++o)
          acc[o] = fmaf(v, wgt[((size_t)o * Cin + c) * 9 + k], acc[o]);
      }
    }
  }
#pragma unroll
  for (int o = 0; o < COUT; ++o) {
    float r = acc[o];
    if (relu) r = fmaxf(r, 0.f);
    out[(((size_t)n * ocstride + ocoff + o) * H + h) * W + w] = r;
  }
}

// ---------------- host-side launch helpers ----------------
static void L_conv(hipStream_t s, const float* in, const float* w, const float* b,
                   float* out, int N, int Cin, int H, int W, int Cout,
                   bool relu, int ocoff, int ocstride) {
  dim3 blk(16, 16, 1), grd((W + 15) / 16, (H + 15) / 16, N);
  size_t lds = (size_t)Cin * 324 * sizeof(float);
  int r = relu ? 1 : 0;
  switch (Cout) {
    case 16: conv3x3_k<16><<<grd, blk, lds, s>>>(in, w, b, out, N, Cin, H, W, r, ocoff, ocstride); break;
    case 18: conv3x3_k<18><<<grd, blk, lds, s>>>(in, w, b, out, N, Cin, H, W, r, ocoff, ocstride); break;
    case 36: conv3x3_k<36><<<grd, blk, lds, s>>>(in, w, b, out, N, Cin, H, W, r, ocoff, ocstride); break;
  }
}

static void L_deform(hipStream_t s, const float* in, const float* off, const float* w,
                     float* out, int N, int Cin, int H, int W, int dg, int Cout,
                     bool relu, int ocoff, int ocstride) {
  dim3 blk(16, 16, 1), grd((W + 15) / 16, (H + 15) / 16, N);
  int r = relu ? 1 : 0;
  switch (Cout) {
    case 16: deform3x3_k<16><<<grd, blk, 0, s>>>(in, off, w, out, N, Cin, H, W, dg, r, ocoff, ocstride); break;
    case 2:  deform3x3_k<2><<<grd, blk, 0, s>>>(in, off, w, out, N, Cin, H, W, dg, r, ocoff, ocstride); break;
  }
}

static void L_pool(hipStream_t s, const float* in, float* out, int NC, int H, int W) {
  int Ho = H / 2, Wo = W / 2;
  int total = NC * Ho * Wo;
  maxpool3s2_k<<<(total + TB - 1) / TB, TB, 0, s>>>(in, out, NC, H, W, Ho, Wo);
}

static void L_up2(hipStream_t s, const float* in, float* out, int N, int C, int H, int W,
                  int ocoff, int ocstride) {
  int total = N * C * 4 * H * W;
  up2_k<<<(total + TB - 1) / TB, TB, 0, s>>>(in, out, N, C, H, W, ocoff, ocstride);
}

static void L_copy(hipStream_t s, const float* src, float* dst, int N, int C, int HW,
                   int ocoff, int ocstride) {
  int total = N * C * HW;
  copych_k<<<(total + TB - 1) / TB, TB, 0, s>>>(src, dst, N, C, HW, ocoff, ocstride);
}

extern "C" void kernel_launch(void* const* d_in, const int* in_sizes, int n_in,
                              void* d_out, int out_size, void* d_ws, size_t ws_size,
                              hipStream_t stream) {
  auto F = [&](int i) { return (const float*)d_in[i]; };
  const float* ref = F(0);
  const float* unr = F(1);
  const float* few1[3] = {F(2), F(6), F(10)};
  const float* feb1[3] = {F(3), F(7), F(11)};
  const float* few2[3] = {F(4), F(8), F(12)};
  const float* feb2[3] = {F(5), F(9), F(13)};
  const float* obw[3] = {F(14), F(16), F(18)};
  const float* obb[3] = {F(15), F(17), F(19)};
  const float* ogw[3] = {F(20), F(22), F(24)};
  const float* ogb[3] = {F(21), F(23), F(25)};
  const float* dcw[3] = {F(26), F(27), F(28)};
  const float* fcw[3] = {F(29), F(31), F(33)};
  const float* fcb[3] = {F(30), F(32), F(34)};
  const float* dobw = F(35);
  const float* dobb = F(36);
  const float* dogw = F(37);
  const float* dogb = F(38);
  const float* ddcw = F(39);

  // ---- workspace layout (floats) ----
  float* ws = (float*)d_ws;
  size_t p = 0;
  auto alloc = [&](size_t nf) { float* r = ws + p; p += nf; return r; };
  const size_t SC = 9437184;  // scratch: fits (4,36,256,256) and per-image (1,16,512,512)
  float* A = alloc(SC);
  float* Bf = alloc(SC);
  float* rf[3], *uf[3], *offs[3], *feats[3];
  rf[0] = alloc((size_t)4 * 16 * 256 * 256);
  uf[0] = alloc((size_t)4 * 16 * 256 * 256);
  rf[1] = alloc((size_t)4 * 16 * 128 * 128);
  uf[1] = alloc((size_t)4 * 16 * 128 * 128);
  rf[2] = alloc((size_t)4 * 16 * 64 * 64);
  uf[2] = alloc((size_t)4 * 16 * 64 * 64);
  offs[0] = alloc((size_t)4 * 18 * 256 * 256);
  offs[1] = alloc((size_t)4 * 18 * 128 * 128);
  offs[2] = alloc((size_t)4 * 18 * 64 * 64);
  feats[0] = alloc((size_t)4 * 16 * 256 * 256);
  feats[1] = alloc((size_t)4 * 16 * 128 * 128);
  feats[2] = alloc((size_t)4 * 16 * 64 * 64);
  if (p * sizeof(float) > ws_size) return;  // ws too small: bail cleanly

  // ---- feature-extraction pyramids ----
  const float* imgs[2] = {ref, unr};
  float** pyr[2] = {rf, uf};
  for (int im = 0; im < 2; ++im) {
    // level 0 at 512^2: per-image to keep temps small
    for (int n = 0; n < 4; ++n) {
      L_conv(stream, imgs[im] + (size_t)n * 512 * 512, few1[0], feb1[0], A, 1, 1, 512, 512, 16, true, 0, 16);
      L_conv(stream, A, few2[0], feb2[0], Bf, 1, 16, 512, 512, 16, true, 0, 16);
      L_pool(stream, Bf, pyr[im][0] + (size_t)n * 16 * 256 * 256, 16, 512, 512);
    }
    // level 1
    L_conv(stream, pyr[im][0], few1[1], feb1[1], A, 4, 16, 256, 256, 16, true, 0, 16);
    L_conv(stream, A, few2[1], feb2[1], Bf, 4, 16, 256, 256, 16, true, 0, 16);
    L_pool(stream, Bf, pyr[im][1], 4 * 16, 256, 256);
    // level 2
    L_conv(stream, pyr[im][1], few1[2], feb1[2], A, 4, 16, 128, 128, 16, true, 0, 16);
    L_conv(stream, A, few2[2], feb2[2], Bf, 4, 16, 128, 128, 16, true, 0, 16);
    L_pool(stream, Bf, pyr[im][2], 4 * 16, 128, 128);
  }

  // ---- coarse-to-fine alignment ----
  int Hs[3] = {256, 128, 64};
  for (int i = 2; i >= 0; --i) {
    int H = Hs[i];
    int hw = H * H;
    // cat(rf,uf) -> A (32ch)
    L_copy(stream, rf[i], A, 4, 16, hw, 0, 32);
    L_copy(stream, uf[i], A, 4, 16, hw, 16, 32);
    if (i == 2) {
      L_conv(stream, A, obw[2], obb[2], Bf, 4, 32, H, H, 16, true, 0, 16);
      L_conv(stream, Bf, ogw[2], ogb[2], offs[2], 4, 16, H, H, 18, true, 0, 18);
      L_deform(stream, uf[2], offs[2], dcw[2], Bf, 4, 16, H, H, 1, 16, true, 0, 16);
      L_conv(stream, Bf, fcw[2], fcb[2], feats[2], 4, 16, H, H, 16, true, 0, 16);
    } else {
      // o (16ch) + up2(offs[i+1]) (18ch) -> Bf as 34ch
      L_conv(stream, A, obw[i], obb[i], Bf, 4, 32, H, H, 16, true, 0, 34);
      L_up2(stream, offs[i + 1], Bf, 4, 18, H / 2, H / 2, 16, 34);
      L_conv(stream, Bf, ogw[i], ogb[i], offs[i], 4, 34, H, H, 18, true, 0, 18);
      // f (16ch) + up2(feats[i+1]) (16ch) -> A as 32ch
      L_deform(stream, uf[i], offs[i], dcw[i], A, 4, 16, H, H, 1, 16, true, 0, 32);
      L_up2(stream, feats[i + 1], A, 4, 16, H / 2, H / 2, 16, 32);
      L_conv(stream, A, fcw[i], fcb[i], feats[i], 4, 32, H, H, 16, true, 0, 16);
    }
  }

  // ---- final offset head + deform (dg=2) ----
  const int hw0 = 256 * 256;
  L_copy(stream, rf[0], A, 4, 16, hw0, 0, 32);
  L_copy(stream, feats[0], A, 4, 16, hw0, 16, 32);
  L_conv(stream, A, dobw, dobb, Bf, 4, 32, 256, 256, 16, false, 0, 34);
  L_copy(stream, offs[0], Bf, 4, 18, hw0, 16, 34);
  L_conv(stream, Bf, dogw, dogb, A, 4, 34, 256, 256, 36, false, 0, 36);
  L_deform(stream, feats[0], A, ddcw, (float*)d_out, 4, 16, 256, 256, 2, 2, false, 0, 2);
}

// Round 2
// 2141.188 us; speedup vs baseline: 1.2113x; 1.2113x over previous
//
#include <hip/hip_runtime.h>
#include <math.h>

#define TB 256

// ---------------- channel-slice copy (for concat) ----------------
__global__ __launch_bounds__(256) void copych_k(
    const float* __restrict__ src, float* __restrict__ dst,
    int N, int C, int HW, int ocoff, int ocstride) {
  int idx = blockIdx.x * TB + threadIdx.x;
  int total = N * C * HW;
  if (idx >= total) return;
  int i = idx % HW;
  int t = idx / HW;
  int c = t % C;
  int n = t / C;
  dst[((size_t)n * ocstride + ocoff + c) * HW + i] = src[idx];
}

// ---------------- maxpool 3x3 stride2 pad1 ----------------
__global__ __launch_bounds__(256) void maxpool3s2_k(
    const float* __restrict__ in, float* __restrict__ out,
    int NC, int H, int W, int Ho, int Wo) {
  int idx = blockIdx.x * TB + threadIdx.x;
  int total = NC * Ho * Wo;
  if (idx >= total) return;
  int wo = idx % Wo;
  int t = idx / Wo;
  int ho = t % Ho;
  int nc = t / Ho;
  const float* src = in + (size_t)nc * H * W;
  int y0 = 2 * ho - 1, x0 = 2 * wo - 1;
  float m = -INFINITY;
  for (int dy = 0; dy < 3; ++dy) {
    int y = y0 + dy;
    if (y < 0 || y >= H) continue;
    for (int dx = 0; dx < 3; ++dx) {
      int x = x0 + dx;
      if (x < 0 || x >= W) continue;
      m = fmaxf(m, src[(size_t)y * W + x]);
    }
  }
  out[idx] = m;
}

// ---------------- bilinear x2 upsample (jax.image.resize, half-pixel) ----------------
__global__ __launch_bounds__(256) void up2_k(
    const float* __restrict__ in, float* __restrict__ out,
    int N, int C, int H, int W, int ocoff, int ocstride) {
  int Ho = 2 * H, Wo = 2 * W;
  int total = N * C * Ho * Wo;
  int idx = blockIdx.x * TB + threadIdx.x;
  if (idx >= total) return;
  int xo = idx % Wo;
  int t = idx / Wo;
  int yo = t % Ho;
  t /= Ho;
  int c = t % C;
  int n = t / C;
  float sy = 0.5f * yo - 0.25f;
  float sx = 0.5f * xo - 0.25f;
  float y0f = floorf(sy), x0f = floorf(sx);
  float wy = sy - y0f, wx = sx - x0f;
  int y0 = (int)y0f, x0 = (int)x0f;
  int y0c = min(max(y0, 0), H - 1), y1c = min(max(y0 + 1, 0), H - 1);
  int x0c = min(max(x0, 0), W - 1), x1c = min(max(x0 + 1, 0), W - 1);
  const float* s = in + ((size_t)n * C + c) * H * W;
  float v = (1.f - wy) * ((1.f - wx) * s[(size_t)y0c * W + x0c] + wx * s[(size_t)y0c * W + x1c]) +
            wy * ((1.f - wx) * s[(size_t)y1c * W + x0c] + wx * s[(size_t)y1c * W + x1c]);
  out[(((size_t)n * ocstride + ocoff + c) * Ho + yo) * Wo + xo] = v;
}

// ---------------- 3x3 conv v2: 32x16 tile, 2 px/thread, chunked LDS ----------------
// block (16,16). Output tile: 32 wide (x: 2 px/thread) x 16 tall.
// LDS: CH channels x 18 rows x 36 pitch (rows 16B-aligned). H%16==0, W%32==0 assumed.
template <int CIN, int COUT>
__global__ __launch_bounds__(256) void conv3x3_v2(
    const float* __restrict__ in, const float* __restrict__ wgt,
    const float* __restrict__ bias, float* __restrict__ out,
    int H, int W, int relu, int ocoff, int ocstride) {
  constexpr int CH = (CIN < 8) ? CIN : 8;
  constexpr int NCHUNK = CIN / CH;
  constexpr int CREM = CIN % CH;
  constexpr int NPASS = NCHUNK + (CREM ? 1 : 0);
  extern __shared__ float lds[];  // CH * 18 * 36 floats
  const int n = blockIdx.z;
  const int bx = blockIdx.x * 32, by = blockIdx.y * 16;
  const int tx = threadIdx.x, ty = threadIdx.y;
  const int tid = ty * 16 + tx;
  const float* inN = in + (size_t)n * CIN * H * W;

  float acc[COUT][2];
#pragma unroll
  for (int o = 0; o < COUT; ++o) {
    float b = bias ? bias[o] : 0.f;
    acc[o][0] = b;
    acc[o][1] = b;
  }

  for (int nc = 0; nc < NPASS; ++nc) {
    const int c0 = nc * CH;
    const int L = (nc < NCHUNK) ? CH : CREM;
    __syncthreads();  // protect LDS from previous pass's readers
    // stage L x 18 x 34 (zero-pad OOB)
    for (int idx = tid; idx < L * 612; idx += 256) {
      int c = idx / 612;
      int r = idx - c * 612;
      int ly = r / 34;
      int lx = r - ly * 34;
      int gy = by + ly - 1, gx = bx + lx - 1;
      float v = 0.f;
      if (gy >= 0 && gy < H && gx >= 0 && gx < W)
        v = inN[((size_t)(c0 + c) * H + gy) * W + gx];
      lds[c * 648 + ly * 36 + lx] = v;
    }
    __syncthreads();
    for (int c = 0; c < L; ++c) {
      const float* ld = lds + c * 648 + ty * 36 + 2 * tx;
      float v[3][4];
#pragma unroll
      for (int dy = 0; dy < 3; ++dy)
#pragma unroll
        for (int dx = 0; dx < 4; ++dx) v[dy][dx] = ld[dy * 36 + dx];
      const float* wc = wgt + (size_t)(c0 + c) * 9;
#pragma unroll
      for (int k = 0; k < 9; ++k) {
        const int ky = k / 3, kx = k - (k / 3) * 3;
#pragma unroll
        for (int o = 0; o < COUT; ++o) {
          float w = wc[(size_t)o * CIN * 9 + k];
          acc[o][0] = fmaf(v[ky][kx], w, acc[o][0]);
          acc[o][1] = fmaf(v[ky][kx + 1], w, acc[o][1]);
        }
      }
    }
  }

  const int h = by + ty, x = bx + 2 * tx;
#pragma unroll
  for (int o = 0; o < COUT; ++o) {
    float r0 = acc[o][0], r1 = acc[o][1];
    if (relu) {
      r0 = fmaxf(r0, 0.f);
      r1 = fmaxf(r1, 0.f);
    }
    float* dst = out + (((size_t)n * ocstride + ocoff + o) * H + h) * W + x;
    *(float2*)dst = make_float2(r0, r1);
  }
}

// ---------------- deformable 3x3 conv (mmcv, no modulation/bias) ----------------
template <int COUT>
__global__ __launch_bounds__(256) void deform3x3_k(
    const float* __restrict__ in, const float* __restrict__ off,
    const float* __restrict__ wgt, float* __restrict__ out,
    int N, int Cin, int H, int W, int dg, int relu, int ocoff, int ocstride) {
  int n = blockIdx.z;
  int h = blockIdx.y * 16 + threadIdx.y;
  int w = blockIdx.x * 16 + threadIdx.x;
  if (h >= H || w >= W) return;
  int Cg = Cin / dg;
  int offC = dg * 18;
  float acc[COUT];
#pragma unroll
  for (int o = 0; o < COUT; ++o) acc[o] = 0.f;
  const float* inN = in + (size_t)n * Cin * H * W;
  const float* offN = off + (size_t)n * offC * H * W;
  for (int g = 0; g < dg; ++g) {
    for (int k = 0; k < 9; ++k) {
      int ky = k / 3 - 1, kx = k % 3 - 1;
      float oy = offN[((size_t)((g * 9 + k) * 2 + 0) * H + h) * W + w];
      float ox = offN[((size_t)((g * 9 + k) * 2 + 1) * H + h) * W + w];
      float py = (float)(h + ky) + oy;
      float px = (float)(w + kx) + ox;
      float y0f = floorf(py), x0f = floorf(px);
      float wy = py - y0f, wx = px - x0f;
      int y0 = (int)y0f, x0 = (int)x0f;
      bool vy0 = (y0 >= 0) && (y0 < H);
      bool vy1 = (y0 + 1 >= 0) && (y0 + 1 < H);
      bool vx0 = (x0 >= 0) && (x0 < W);
      bool vx1 = (x0 + 1 >= 0) && (x0 + 1 < W);
      int y0c = min(max(y0, 0), H - 1), y1c = min(max(y0 + 1, 0), H - 1);
      int x0c = min(max(x0, 0), W - 1), x1c = min(max(x0 + 1, 0), W - 1);
      float w00 = (1.f - wy) * (1.f - wx), w01 = (1.f - wy) * wx;
      float w10 = wy * (1.f - wx), w11 = wy * wx;
      for (int ci = 0; ci < Cg; ++ci) {
        int c = g * Cg + ci;
        const float* s = inN + (size_t)c * H * W;
        float v00 = (vy0 && vx0) ? s[(size_t)y0c * W + x0c] : 0.f;
        float v01 = (vy0 && vx1) ? s[(size_t)y0c * W + x1c] : 0.f;
        float v10 = (vy1 && vx0) ? s[(size_t)y1c * W + x0c] : 0.f;
        float v11 = (vy1 && vx1) ? s[(size_t)y1c * W + x1c] : 0.f;
        float v = w00 * v00 + w01 * v01 + w10 * v10 + w11 * v11;
#pragma unroll
        for (int o = 0; o < COUT; ++o)
          acc[o] = fmaf(v, wgt[((size_t)o * Cin + c) * 9 + k], acc[o]);
      }
    }
  }
#pragma unroll
  for (int o = 0; o < COUT; ++o) {
    float r = acc[o];
    if (relu) r = fmaxf(r, 0.f);
    out[(((size_t)n * ocstride + ocoff + o) * H + h) * W + w] = r;
  }
}

// ---------------- host-side launch helpers ----------------
static void L_conv(hipStream_t s, const float* in, const float* w, const float* b,
                   float* out, int N, int Cin, int H, int W, int Cout,
                   bool relu, int ocoff, int ocstride) {
  dim3 blk(16, 16, 1), grd(W / 32, H / 16, N);
  int r = relu ? 1 : 0;
  size_t lds = (size_t)((Cin < 8) ? Cin : 8) * 18 * 36 * sizeof(float);
  if (Cin == 1 && Cout == 16)
    conv3x3_v2<1, 16><<<grd, blk, lds, s>>>(in, w, b, out, H, W, r, ocoff, ocstride);
  else if (Cin == 16 && Cout == 16)
    conv3x3_v2<16, 16><<<grd, blk, lds, s>>>(in, w, b, out, H, W, r, ocoff, ocstride);
  else if (Cin == 16 && Cout == 18)
    conv3x3_v2<16, 18><<<grd, blk, lds, s>>>(in, w, b, out, H, W, r, ocoff, ocstride);
  else if (Cin == 32 && Cout == 16)
    conv3x3_v2<32, 16><<<grd, blk, lds, s>>>(in, w, b, out, H, W, r, ocoff, ocstride);
  else if (Cin == 34 && Cout == 18)
    conv3x3_v2<34, 18><<<grd, blk, lds, s>>>(in, w, b, out, H, W, r, ocoff, ocstride);
  else if (Cin == 34 && Cout == 36) {  // split into two 18-out halves
    conv3x3_v2<34, 18><<<grd, blk, lds, s>>>(in, w, b, out, H, W, r, ocoff, ocstride);
    conv3x3_v2<34, 18><<<grd, blk, lds, s>>>(in, w + (size_t)18 * 34 * 9, b ? b + 18 : b,
                                             out, H, W, r, ocoff + 18, ocstride);
  }
}

static void L_deform(hipStream_t s, const float* in, const float* off, const float* w,
                     float* out, int N, int Cin, int H, int W, int dg, int Cout,
                     bool relu, int ocoff, int ocstride) {
  dim3 blk(16, 16, 1), grd((W + 15) / 16, (H + 15) / 16, N);
  int r = relu ? 1 : 0;
  switch (Cout) {
    case 16: deform3x3_k<16><<<grd, blk, 0, s>>>(in, off, w, out, N, Cin, H, W, dg, r, ocoff, ocstride); break;
    case 2:  deform3x3_k<2><<<grd, blk, 0, s>>>(in, off, w, out, N, Cin, H, W, dg, r, ocoff, ocstride); break;
  }
}

static void L_pool(hipStream_t s, const float* in, float* out, int NC, int H, int W) {
  int Ho = H / 2, Wo = W / 2;
  int total = NC * Ho * Wo;
  maxpool3s2_k<<<(total + TB - 1) / TB, TB, 0, s>>>(in, out, NC, H, W, Ho, Wo);
}

static void L_up2(hipStream_t s, const float* in, float* out, int N, int C, int H, int W,
                  int ocoff, int ocstride) {
  int total = N * C * 4 * H * W;
  up2_k<<<(total + TB - 1) / TB, TB, 0, s>>>(in, out, N, C, H, W, ocoff, ocstride);
}

static void L_copy(hipStream_t s, const float* src, float* dst, int N, int C, int HW,
                   int ocoff, int ocstride) {
  int total = N * C * HW;
  copych_k<<<(total + TB - 1) / TB, TB, 0, s>>>(src, dst, N, C, HW, ocoff, ocstride);
}

extern "C" void kernel_launch(void* const* d_in, const int* in_sizes, int n_in,
                              void* d_out, int out_size, void* d_ws, size_t ws_size,
                              hipStream_t stream) {
  auto F = [&](int i) { return (const float*)d_in[i]; };
  const float* ref = F(0);
  const float* unr = F(1);
  const float* few1[3] = {F(2), F(6), F(10)};
  const float* feb1[3] = {F(3), F(7), F(11)};
  const float* few2[3] = {F(4), F(8), F(12)};
  const float* feb2[3] = {F(5), F(9), F(13)};
  const float* obw[3] = {F(14), F(16), F(18)};
  const float* obb[3] = {F(15), F(17), F(19)};
  const float* ogw[3] = {F(20), F(22), F(24)};
  const float* ogb[3] = {F(21), F(23), F(25)};
  const float* dcw[3] = {F(26), F(27), F(28)};
  const float* fcw[3] = {F(29), F(31), F(33)};
  const float* fcb[3] = {F(30), F(32), F(34)};
  const float* dobw = F(35);
  const float* dobb = F(36);
  const float* dogw = F(37);
  const float* dogb = F(38);
  const float* ddcw = F(39);

  // ---- workspace layout (floats) ----
  float* ws = (float*)d_ws;
  size_t p = 0;
  auto alloc = [&](size_t nf) { float* r = ws + p; p += nf; return r; };
  const size_t SC = 9437184;  // fits (4,36,256,256) and (2,16,512,512)
  float* A = alloc(SC);
  float* Bf = alloc(SC);
  float* rf[3], *uf[3], *offs[3], *feats[3];
  rf[0] = alloc((size_t)4 * 16 * 256 * 256);
  uf[0] = alloc((size_t)4 * 16 * 256 * 256);
  rf[1] = alloc((size_t)4 * 16 * 128 * 128);
  uf[1] = alloc((size_t)4 * 16 * 128 * 128);
  rf[2] = alloc((size_t)4 * 16 * 64 * 64);
  uf[2] = alloc((size_t)4 * 16 * 64 * 64);
  offs[0] = alloc((size_t)4 * 18 * 256 * 256);
  offs[1] = alloc((size_t)4 * 18 * 128 * 128);
  offs[2] = alloc((size_t)4 * 18 * 64 * 64);
  feats[0] = alloc((size_t)4 * 16 * 256 * 256);
  feats[1] = alloc((size_t)4 * 16 * 128 * 128);
  feats[2] = alloc((size_t)4 * 16 * 64 * 64);
  if (p * sizeof(float) > ws_size) return;  // ws too small: bail cleanly

  // ---- feature-extraction pyramids ----
  const float* imgs[2] = {ref, unr};
  float** pyr[2] = {rf, uf};
  for (int im = 0; im < 2; ++im) {
    // level 0 at 512^2, in two N=2 chunks (keeps temps <= SC)
    for (int ch = 0; ch < 2; ++ch) {
      const float* src = imgs[im] + (size_t)ch * 2 * 512 * 512;
      L_conv(stream, src, few1[0], feb1[0], A, 2, 1, 512, 512, 16, true, 0, 16);
      L_conv(stream, A, few2[0], feb2[0], Bf, 2, 16, 512, 512, 16, true, 0, 16);
      L_pool(stream, Bf, pyr[im][0] + (size_t)ch * 2 * 16 * 256 * 256, 2 * 16, 512, 512);
    }
    // level 1
    L_conv(stream, pyr[im][0], few1[1], feb1[1], A, 4, 16, 256, 256, 16, true, 0, 16);
    L_conv(stream, A, few2[1], feb2[1], Bf, 4, 16, 256, 256, 16, true, 0, 16);
    L_pool(stream, Bf, pyr[im][1], 4 * 16, 256, 256);
    // level 2
    L_conv(stream, pyr[im][1], few1[2], feb1[2], A, 4, 16, 128, 128, 16, true, 0, 16);
    L_conv(stream, A, few2[2], feb2[2], Bf, 4, 16, 128, 128, 16, true, 0, 16);
    L_pool(stream, Bf, pyr[im][2], 4 * 16, 128, 128);
  }

  // ---- coarse-to-fine alignment ----
  int Hs[3] = {256, 128, 64};
  for (int i = 2; i >= 0; --i) {
    int H = Hs[i];
    int hw = H * H;
    L_copy(stream, rf[i], A, 4, 16, hw, 0, 32);
    L_copy(stream, uf[i], A, 4, 16, hw, 16, 32);
    if (i == 2) {
      L_conv(stream, A, obw[2], obb[2], Bf, 4, 32, H, H, 16, true, 0, 16);
      L_conv(stream, Bf, ogw[2], ogb[2], offs[2], 4, 16, H, H, 18, true, 0, 18);
      L_deform(stream, uf[2], offs[2], dcw[2], Bf, 4, 16, H, H, 1, 16, true, 0, 16);
      L_conv(stream, Bf, fcw[2], fcb[2], feats[2], 4, 16, H, H, 16, true, 0, 16);
    } else {
      L_conv(stream, A, obw[i], obb[i], Bf, 4, 32, H, H, 16, true, 0, 34);
      L_up2(stream, offs[i + 1], Bf, 4, 18, H / 2, H / 2, 16, 34);
      L_conv(stream, Bf, ogw[i], ogb[i], offs[i], 4, 34, H, H, 18, true, 0, 18);
      L_deform(stream, uf[i], offs[i], dcw[i], A, 4, 16, H, H, 1, 16, true, 0, 32);
      L_up2(stream, feats[i + 1], A, 4, 16, H / 2, H / 2, 16, 32);
      L_conv(stream, A, fcw[i], fcb[i], feats[i], 4, 32, H, H, 16, true, 0, 16);
    }
  }

  // ---- final offset head + deform (dg=2) ----
  const int hw0 = 256 * 256;
  L_copy(stream, rf[0], A, 4, 16, hw0, 0, 32);
  L_copy(stream, feats[0], A, 4, 16, hw0, 16, 32);
  L_conv(stream, A, dobw, dobb, Bf, 4, 32, 256, 256, 16, false, 0, 34);
  L_copy(stream, offs[0], Bf, 4, 18, hw0, 16, 34);
  L_conv(stream, Bf, dogw, dogb, A, 4, 34, 256, 256, 36, false, 0, 36);
  L_deform(stream, feats[0], A, ddcw, (float*)d_out, 4, 16, 256, 256, 2, 2, false, 0, 2);
}

// Round 3
// 1962.483 us; speedup vs baseline: 1.3216x; 1.0911x over previous
//
#include <hip/hip_runtime.h>
#include <math.h>

#define TB 256

// ---------------- channel-slice copy (for concat) ----------------
__global__ __launch_bounds__(256) void copych_k(
    const float* __restrict__ src, float* __restrict__ dst,
    int N, int C, int HW, int ocoff, int ocstride) {
  int idx = blockIdx.x * TB + threadIdx.x;
  int total = N * C * HW;
  if (idx >= total) return;
  int i = idx % HW;
  int t = idx / HW;
  int c = t % C;
  int n = t / C;
  dst[((size_t)n * ocstride + ocoff + c) * HW + i] = src[idx];
}

// ---------------- maxpool 3x3 stride2 pad1 ----------------
__global__ __launch_bounds__(256) void maxpool3s2_k(
    const float* __restrict__ in, float* __restrict__ out,
    int NC, int H, int W, int Ho, int Wo) {
  int idx = blockIdx.x * TB + threadIdx.x;
  int total = NC * Ho * Wo;
  if (idx >= total) return;
  int wo = idx % Wo;
  int t = idx / Wo;
  int ho = t % Ho;
  int nc = t / Ho;
  const float* src = in + (size_t)nc * H * W;
  int y0 = 2 * ho - 1, x0 = 2 * wo - 1;
  float m = -INFINITY;
  for (int dy = 0; dy < 3; ++dy) {
    int y = y0 + dy;
    if (y < 0 || y >= H) continue;
    for (int dx = 0; dx < 3; ++dx) {
      int x = x0 + dx;
      if (x < 0 || x >= W) continue;
      m = fmaxf(m, src[(size_t)y * W + x]);
    }
  }
  out[idx] = m;
}

// ---------------- bilinear x2 upsample (jax.image.resize, half-pixel) ----------------
__global__ __launch_bounds__(256) void up2_k(
    const float* __restrict__ in, float* __restrict__ out,
    int N, int C, int H, int W, int ocoff, int ocstride) {
  int Ho = 2 * H, Wo = 2 * W;
  int total = N * C * Ho * Wo;
  int idx = blockIdx.x * TB + threadIdx.x;
  if (idx >= total) return;
  int xo = idx % Wo;
  int t = idx / Wo;
  int yo = t % Ho;
  t /= Ho;
  int c = t % C;
  int n = t / C;
  float sy = 0.5f * yo - 0.25f;
  float sx = 0.5f * xo - 0.25f;
  float y0f = floorf(sy), x0f = floorf(sx);
  float wy = sy - y0f, wx = sx - x0f;
  int y0 = (int)y0f, x0 = (int)x0f;
  int y0c = min(max(y0, 0), H - 1), y1c = min(max(y0 + 1, 0), H - 1);
  int x0c = min(max(x0, 0), W - 1), x1c = min(max(x0 + 1, 0), W - 1);
  const float* s = in + ((size_t)n * C + c) * H * W;
  float v = (1.f - wy) * ((1.f - wx) * s[(size_t)y0c * W + x0c] + wx * s[(size_t)y0c * W + x1c]) +
            wy * ((1.f - wx) * s[(size_t)y1c * W + x0c] + wx * s[(size_t)y1c * W + x1c]);
  out[(((size_t)n * ocstride + ocoff + c) * Ho + yo) * Wo + xo] = v;
}

// ---------------- CHW -> HWC transpose (C=16), LDS tiled ----------------
// block: 256 thr, tile = 16 ch x 64 px. HW % 64 == 0.
__global__ __launch_bounds__(256) void chw2hwc16_k(
    const float* __restrict__ src, float* __restrict__ dst, int HW) {
  __shared__ float t[16 * 65];
  int n = blockIdx.y;
  int p0 = blockIdx.x * 64;
  int tid = threadIdx.x;
  for (int e = tid; e < 1024; e += 256) {
    int c = e >> 6, j = e & 63;
    t[c * 65 + j] = src[((size_t)n * 16 + c) * HW + p0 + j];
  }
  __syncthreads();
  for (int e = tid; e < 1024; e += 256) {
    int j = e >> 4, c = e & 15;
    dst[((size_t)n * HW + p0 + j) * 16 + c] = t[c * 65 + j];
  }
}

// ---------------- deform weight reorder: (O,16,9) -> (9,16,O) ----------------
// out: [0..2303] dc0, [2304..] dc1, [4608..] dc2, [6912..7199] ddc (O=2)
__global__ __launch_bounds__(256) void wreorder_k(
    const float* __restrict__ a, const float* __restrict__ b,
    const float* __restrict__ c, const float* __restrict__ d,
    float* __restrict__ out) {
  int t = blockIdx.x * 256 + threadIdx.x;
  if (t < 6912) {
    int which = t / 2304, r = t % 2304;
    int o = r % 16, kc = r / 16;
    int ci = kc % 16, k = kc / 16;
    const float* w = which == 0 ? a : (which == 1 ? b : c);
    out[t] = w[(o * 16 + ci) * 9 + k];
  } else if (t < 7200) {
    int r = t - 6912;
    int o = r % 2, kc = r / 2;
    int ci = kc % 16, k = kc / 16;
    out[t] = d[(o * 16 + ci) * 9 + k];
  }
}

// ---------------- 3x3 conv v2: 32x16 tile, 2 px/thread, chunked LDS ----------------
template <int CIN, int COUT>
__global__ __launch_bounds__(256) void conv3x3_v2(
    const float* __restrict__ in, const float* __restrict__ wgt,
    const float* __restrict__ bias, float* __restrict__ out,
    int H, int W, int relu, int ocoff, int ocstride) {
  constexpr int CH = (CIN < 8) ? CIN : 8;
  constexpr int NCHUNK = CIN / CH;
  constexpr int CREM = CIN % CH;
  constexpr int NPASS = NCHUNK + (CREM ? 1 : 0);
  extern __shared__ float lds[];  // CH * 18 * 36 floats
  const int n = blockIdx.z;
  const int bx = blockIdx.x * 32, by = blockIdx.y * 16;
  const int tx = threadIdx.x, ty = threadIdx.y;
  const int tid = ty * 16 + tx;
  const float* inN = in + (size_t)n * CIN * H * W;

  float acc[COUT][2];
#pragma unroll
  for (int o = 0; o < COUT; ++o) {
    float b = bias ? bias[o] : 0.f;
    acc[o][0] = b;
    acc[o][1] = b;
  }

  for (int nc = 0; nc < NPASS; ++nc) {
    const int c0 = nc * CH;
    const int L = (nc < NCHUNK) ? CH : CREM;
    __syncthreads();
    for (int idx = tid; idx < L * 612; idx += 256) {
      int c = idx / 612;
      int r = idx - c * 612;
      int ly = r / 34;
      int lx = r - ly * 34;
      int gy = by + ly - 1, gx = bx + lx - 1;
      float v = 0.f;
      if (gy >= 0 && gy < H && gx >= 0 && gx < W)
        v = inN[((size_t)(c0 + c) * H + gy) * W + gx];
      lds[c * 648 + ly * 36 + lx] = v;
    }
    __syncthreads();
    for (int c = 0; c < L; ++c) {
      const float* ld = lds + c * 648 + ty * 36 + 2 * tx;
      float v[3][4];
#pragma unroll
      for (int dy = 0; dy < 3; ++dy)
#pragma unroll
        for (int dx = 0; dx < 4; ++dx) v[dy][dx] = ld[dy * 36 + dx];
      const float* wc = wgt + (size_t)(c0 + c) * 9;
#pragma unroll
      for (int k = 0; k < 9; ++k) {
        const int ky = k / 3, kx = k - (k / 3) * 3;
#pragma unroll
        for (int o = 0; o < COUT; ++o) {
          float w = wc[(size_t)o * CIN * 9 + k];
          acc[o][0] = fmaf(v[ky][kx], w, acc[o][0]);
          acc[o][1] = fmaf(v[ky][kx + 1], w, acc[o][1]);
        }
      }
    }
  }

  const int h = by + ty, x = bx + 2 * tx;
#pragma unroll
  for (int o = 0; o < COUT; ++o) {
    float r0 = acc[o][0], r1 = acc[o][1];
    if (relu) {
      r0 = fmaxf(r0, 0.f);
      r1 = fmaxf(r1, 0.f);
    }
    float* dst = out + (((size_t)n * ocstride + ocoff + o) * H + h) * W + x;
    *(float2*)dst = make_float2(r0, r1);
  }
}

// ---------------- deformable 3x3 conv v3: HWC input, (k,c,o) weights ----------------
// thread = one output pixel, all COUT outputs. CIN=16. H*W % 256 == 0.
template <int COUT, int DG>
__global__ __launch_bounds__(256) void deform_v3(
    const float* __restrict__ inHWC, const float* __restrict__ off,
    const float* __restrict__ wt, float* __restrict__ out,
    int H, int W, int relu, int ocoff, int ocstride) {
  constexpr int CIN = 16;
  constexpr int CG = CIN / DG;
  const int n = blockIdx.y;
  const int HWt = H * W;
  const int hw = blockIdx.x * 256 + threadIdx.x;
  const int h = hw / W, w = hw - h * W;
  const float* inN = inHWC + (size_t)n * HWt * CIN;
  const float* offN = off + (size_t)n * (DG * 18) * HWt + hw;
  float acc[COUT];
#pragma unroll
  for (int o = 0; o < COUT; ++o) acc[o] = 0.f;
#pragma unroll
  for (int g = 0; g < DG; ++g) {
#pragma unroll
    for (int k = 0; k < 9; ++k) {
      const int ky = k / 3 - 1, kx = k % 3 - 1;
      float oy = offN[(size_t)((g * 9 + k) * 2 + 0) * HWt];
      float ox = offN[(size_t)((g * 9 + k) * 2 + 1) * HWt];
      float py = (float)(h + ky) + oy;
      float px = (float)(w + kx) + ox;
      float y0f = floorf(py), x0f = floorf(px);
      float fy = py - y0f, fx = px - x0f;
      int y0 = (int)y0f, x0 = (int)x0f;
      bool vy0 = ((unsigned)y0 < (unsigned)H);
      bool vy1 = ((unsigned)(y0 + 1) < (unsigned)H);
      bool vx0 = ((unsigned)x0 < (unsigned)W);
      bool vx1 = ((unsigned)(x0 + 1) < (unsigned)W);
      int y0c = min(max(y0, 0), H - 1), y1c = min(max(y0 + 1, 0), H - 1);
      int x0c = min(max(x0, 0), W - 1), x1c = min(max(x0 + 1, 0), W - 1);
      float w00 = (vy0 && vx0) ? (1.f - fy) * (1.f - fx) : 0.f;
      float w01 = (vy0 && vx1) ? (1.f - fy) * fx : 0.f;
      float w10 = (vy1 && vx0) ? fy * (1.f - fx) : 0.f;
      float w11 = (vy1 && vx1) ? fy * fx : 0.f;
      const float* p00 = inN + ((size_t)y0c * W + x0c) * CIN + g * CG;
      const float* p01 = inN + ((size_t)y0c * W + x1c) * CIN + g * CG;
      const float* p10 = inN + ((size_t)y1c * W + x0c) * CIN + g * CG;
      const float* p11 = inN + ((size_t)y1c * W + x1c) * CIN + g * CG;
      const float* wk = wt + (k * CIN + g * CG) * COUT;
#pragma unroll
      for (int c4 = 0; c4 < CG / 4; ++c4) {
        float4 a00 = *(const float4*)(p00 + c4 * 4);
        float4 a01 = *(const float4*)(p01 + c4 * 4);
        float4 a10 = *(const float4*)(p10 + c4 * 4);
        float4 a11 = *(const float4*)(p11 + c4 * 4);
        float v0 = w00 * a00.x + w01 * a01.x + w10 * a10.x + w11 * a11.x;
        float v1 = w00 * a00.y + w01 * a01.y + w10 * a10.y + w11 * a11.y;
        float v2 = w00 * a00.z + w01 * a01.z + w10 * a10.z + w11 * a11.z;
        float v3 = w00 * a00.w + w01 * a01.w + w10 * a10.w + w11 * a11.w;
#pragma unroll
        for (int o = 0; o < COUT; ++o) {
          float t0 = fmaf(v0, wk[(c4 * 4 + 0) * COUT + o], acc[o]);
          t0 = fmaf(v1, wk[(c4 * 4 + 1) * COUT + o], t0);
          t0 = fmaf(v2, wk[(c4 * 4 + 2) * COUT + o], t0);
          acc[o] = fmaf(v3, wk[(c4 * 4 + 3) * COUT + o], t0);
        }
      }
    }
  }
  float* outN = out + ((size_t)n * ocstride + ocoff) * HWt + hw;
#pragma unroll
  for (int o = 0; o < COUT; ++o) {
    float r = acc[o];
    if (relu) r = fmaxf(r, 0.f);
    outN[(size_t)o * HWt] = r;
  }
}

// ---------------- host-side launch helpers ----------------
static void L_conv(hipStream_t s, const float* in, const float* w, const float* b,
                   float* out, int N, int Cin, int H, int W, int Cout,
                   bool relu, int ocoff, int ocstride) {
  dim3 blk(16, 16, 1), grd(W / 32, H / 16, N);
  int r = relu ? 1 : 0;
  size_t lds = (size_t)((Cin < 8) ? Cin : 8) * 18 * 36 * sizeof(float);
  if (Cin == 1 && Cout == 16)
    conv3x3_v2<1, 16><<<grd, blk, lds, s>>>(in, w, b, out, H, W, r, ocoff, ocstride);
  else if (Cin == 16 && Cout == 16)
    conv3x3_v2<16, 16><<<grd, blk, lds, s>>>(in, w, b, out, H, W, r, ocoff, ocstride);
  else if (Cin == 16 && Cout == 18)
    conv3x3_v2<16, 18><<<grd, blk, lds, s>>>(in, w, b, out, H, W, r, ocoff, ocstride);
  else if (Cin == 32 && Cout == 16)
    conv3x3_v2<32, 16><<<grd, blk, lds, s>>>(in, w, b, out, H, W, r, ocoff, ocstride);
  else if (Cin == 34 && Cout == 18)
    conv3x3_v2<34, 18><<<grd, blk, lds, s>>>(in, w, b, out, H, W, r, ocoff, ocstride);
  else if (Cin == 34 && Cout == 36) {  // split into two 18-out halves
    conv3x3_v2<34, 18><<<grd, blk, lds, s>>>(in, w, b, out, H, W, r, ocoff, ocstride);
    conv3x3_v2<34, 18><<<grd, blk, lds, s>>>(in, w + (size_t)18 * 34 * 9, b ? b + 18 : b,
                                             out, H, W, r, ocoff + 18, ocstride);
  }
}

static void L_deform3(hipStream_t s, const float* inHWC, const float* off, const float* wt,
                      float* out, int N, int H, int W, int dg, int Cout, bool relu,
                      int ocoff, int ocstride) {
  dim3 grd(H * W / 256, N);
  int r = relu ? 1 : 0;
  if (Cout == 16 && dg == 1)
    deform_v3<16, 1><<<grd, 256, 0, s>>>(inHWC, off, wt, out, H, W, r, ocoff, ocstride);
  else if (Cout == 2 && dg == 2)
    deform_v3<2, 2><<<grd, 256, 0, s>>>(inHWC, off, wt, out, H, W, r, ocoff, ocstride);
}

static void L_hwc(hipStream_t s, const float* src, float* dst, int N, int HW) {
  dim3 grd(HW / 64, N);
  chw2hwc16_k<<<grd, 256, 0, s>>>(src, dst, HW);
}

static void L_pool(hipStream_t s, const float* in, float* out, int NC, int H, int W) {
  int Ho = H / 2, Wo = W / 2;
  int total = NC * Ho * Wo;
  maxpool3s2_k<<<(total + TB - 1) / TB, TB, 0, s>>>(in, out, NC, H, W, Ho, Wo);
}

static void L_up2(hipStream_t s, const float* in, float* out, int N, int C, int H, int W,
                  int ocoff, int ocstride) {
  int total = N * C * 4 * H * W;
  up2_k<<<(total + TB - 1) / TB, TB, 0, s>>>(in, out, N, C, H, W, ocoff, ocstride);
}

static void L_copy(hipStream_t s, const float* src, float* dst, int N, int C, int HW,
                   int ocoff, int ocstride) {
  int total = N * C * HW;
  copych_k<<<(total + TB - 1) / TB, TB, 0, s>>>(src, dst, N, C, HW, ocoff, ocstride);
}

extern "C" void kernel_launch(void* const* d_in, const int* in_sizes, int n_in,
                              void* d_out, int out_size, void* d_ws, size_t ws_size,
                              hipStream_t stream) {
  auto F = [&](int i) { return (const float*)d_in[i]; };
  const float* ref = F(0);
  const float* unr = F(1);
  const float* few1[3] = {F(2), F(6), F(10)};
  const float* feb1[3] = {F(3), F(7), F(11)};
  const float* few2[3] = {F(4), F(8), F(12)};
  const float* feb2[3] = {F(5), F(9), F(13)};
  const float* obw[3] = {F(14), F(16), F(18)};
  const float* obb[3] = {F(15), F(17), F(19)};
  const float* ogw[3] = {F(20), F(22), F(24)};
  const float* ogb[3] = {F(21), F(23), F(25)};
  const float* dcw[3] = {F(26), F(27), F(28)};
  const float* fcw[3] = {F(29), F(31), F(33)};
  const float* fcb[3] = {F(30), F(32), F(34)};
  const float* dobw = F(35);
  const float* dobb = F(36);
  const float* dogw = F(37);
  const float* dogb = F(38);
  const float* ddcw = F(39);

  // ---- workspace layout (floats) ----
  float* ws = (float*)d_ws;
  size_t p = 0;
  auto alloc = [&](size_t nf) { float* r = ws + p; p += nf; return r; };
  const size_t SC = 9437184;  // fits (4,36,256,256), (2,16,512,512), (4,256*256,16) HWC
  float* A = alloc(SC);
  float* Bf = alloc(SC);
  float* rf[3], *uf[3], *offs[3], *feats[3];
  rf[0] = alloc((size_t)4 * 16 * 256 * 256);
  uf[0] = alloc((size_t)4 * 16 * 256 * 256);
  rf[1] = alloc((size_t)4 * 16 * 128 * 128);
  uf[1] = alloc((size_t)4 * 16 * 128 * 128);
  rf[2] = alloc((size_t)4 * 16 * 64 * 64);
  uf[2] = alloc((size_t)4 * 16 * 64 * 64);
  offs[0] = alloc((size_t)4 * 18 * 256 * 256);
  offs[1] = alloc((size_t)4 * 18 * 128 * 128);
  offs[2] = alloc((size_t)4 * 18 * 64 * 64);
  feats[0] = alloc((size_t)4 * 16 * 256 * 256);
  feats[1] = alloc((size_t)4 * 16 * 128 * 128);
  feats[2] = alloc((size_t)4 * 16 * 64 * 64);
  float* wt = alloc(7200);  // reordered deform weights (9,16,O)
  if (p * sizeof(float) > ws_size) return;  // ws too small: bail cleanly
  const float* wt_dc[3] = {wt, wt + 2304, wt + 4608};
  const float* wt_ddc = wt + 6912;

  // reorder deform weights once (per call)
  wreorder_k<<<29, 256, 0, stream>>>(dcw[0], dcw[1], dcw[2], ddcw, wt);

  // ---- feature-extraction pyramids ----
  const float* imgs[2] = {ref, unr};
  float** pyr[2] = {rf, uf};
  for (int im = 0; im < 2; ++im) {
    for (int ch = 0; ch < 2; ++ch) {  // 512^2 level in two N=2 chunks
      const float* src = imgs[im] + (size_t)ch * 2 * 512 * 512;
      L_conv(stream, src, few1[0], feb1[0], A, 2, 1, 512, 512, 16, true, 0, 16);
      L_conv(stream, A, few2[0], feb2[0], Bf, 2, 16, 512, 512, 16, true, 0, 16);
      L_pool(stream, Bf, pyr[im][0] + (size_t)ch * 2 * 16 * 256 * 256, 2 * 16, 512, 512);
    }
    L_conv(stream, pyr[im][0], few1[1], feb1[1], A, 4, 16, 256, 256, 16, true, 0, 16);
    L_conv(stream, A, few2[1], feb2[1], Bf, 4, 16, 256, 256, 16, true, 0, 16);
    L_pool(stream, Bf, pyr[im][1], 4 * 16, 256, 256);
    L_conv(stream, pyr[im][1], few1[2], feb1[2], A, 4, 16, 128, 128, 16, true, 0, 16);
    L_conv(stream, A, few2[2], feb2[2], Bf, 4, 16, 128, 128, 16, true, 0, 16);
    L_pool(stream, Bf, pyr[im][2], 4 * 16, 128, 128);
  }

  // ---- coarse-to-fine alignment ----
  int Hs[3] = {256, 128, 64};
  for (int i = 2; i >= 0; --i) {
    int H = Hs[i];
    int hw = H * H;
    L_copy(stream, rf[i], A, 4, 16, hw, 0, 32);
    L_copy(stream, uf[i], A, 4, 16, hw, 16, 32);
    if (i == 2) {
      L_conv(stream, A, obw[2], obb[2], Bf, 4, 32, H, H, 16, true, 0, 16);
      L_conv(stream, Bf, ogw[2], ogb[2], offs[2], 4, 16, H, H, 18, true, 0, 18);
      L_hwc(stream, uf[2], A, 4, hw);  // A free (consumed by ob conv)
      L_deform3(stream, A, offs[2], wt_dc[2], Bf, 4, H, H, 1, 16, true, 0, 16);
      L_conv(stream, Bf, fcw[2], fcb[2], feats[2], 4, 16, H, H, 16, true, 0, 16);
    } else {
      L_conv(stream, A, obw[i], obb[i], Bf, 4, 32, H, H, 16, true, 0, 34);
      L_up2(stream, offs[i + 1], Bf, 4, 18, H / 2, H / 2, 16, 34);
      L_conv(stream, Bf, ogw[i], ogb[i], offs[i], 4, 34, H, H, 18, true, 0, 18);
      L_hwc(stream, uf[i], A, 4, hw);  // A free (consumed by ob conv)
      L_deform3(stream, A, offs[i], wt_dc[i], Bf, 4, H, H, 1, 16, true, 0, 32);
      L_up2(stream, feats[i + 1], Bf, 4, 16, H / 2, H / 2, 16, 32);
      L_conv(stream, Bf, fcw[i], fcb[i], feats[i], 4, 32, H, H, 16, true, 0, 16);
    }
  }

  // ---- final offset head + deform (dg=2) ----
  const int hw0 = 256 * 256;
  L_copy(stream, rf[0], A, 4, 16, hw0, 0, 32);
  L_copy(stream, feats[0], A, 4, 16, hw0, 16, 32);
  L_conv(stream, A, dobw, dobb, Bf, 4, 32, 256, 256, 16, false, 0, 34);
  L_copy(stream, offs[0], Bf, 4, 18, hw0, 16, 34);
  L_conv(stream, Bf, dogw, dogb, A, 4, 34, 256, 256, 36, false, 0, 36);
  L_hwc(stream, feats[0], Bf, 4, hw0);  // Bf free (consumed by dog conv)
  L_deform3(stream, Bf, A, wt_ddc, (float*)d_out, 4, 256, 256, 2, 2, false, 0, 2);
}

// Round 4
// 1518.989 us; speedup vs baseline: 1.7074x; 1.2920x over previous
//
#include <hip/hip_runtime.h>
#include <math.h>

#define TB 256

// ---------------- maxpool 3x3 stride2 pad1 ----------------
__global__ __launch_bounds__(256) void maxpool3s2_k(
    const float* __restrict__ in, float* __restrict__ out,
    int NC, int H, int W, int Ho, int Wo) {
  int idx = blockIdx.x * TB + threadIdx.x;
  int total = NC * Ho * Wo;
  if (idx >= total) return;
  int wo = idx % Wo;
  int t = idx / Wo;
  int ho = t % Ho;
  int nc = t / Ho;
  const float* src = in + (size_t)nc * H * W;
  int y0 = 2 * ho - 1, x0 = 2 * wo - 1;
  float m = -INFINITY;
  for (int dy = 0; dy < 3; ++dy) {
    int y = y0 + dy;
    if (y < 0 || y >= H) continue;
    for (int dx = 0; dx < 3; ++dx) {
      int x = x0 + dx;
      if (x < 0 || x >= W) continue;
      m = fmaxf(m, src[(size_t)y * W + x]);
    }
  }
  out[idx] = m;
}

// ---------------- bilinear x2 upsample (jax.image.resize, half-pixel) ----------------
__global__ __launch_bounds__(256) void up2_k(
    const float* __restrict__ in, float* __restrict__ out,
    int N, int C, int H, int W, int ocoff, int ocstride) {
  int Ho = 2 * H, Wo = 2 * W;
  int total = N * C * Ho * Wo;
  int idx = blockIdx.x * TB + threadIdx.x;
  if (idx >= total) return;
  int xo = idx % Wo;
  int t = idx / Wo;
  int yo = t % Ho;
  t /= Ho;
  int c = t % C;
  int n = t / C;
  float sy = 0.5f * yo - 0.25f;
  float sx = 0.5f * xo - 0.25f;
  float y0f = floorf(sy), x0f = floorf(sx);
  float wy = sy - y0f, wx = sx - x0f;
  int y0 = (int)y0f, x0 = (int)x0f;
  int y0c = min(max(y0, 0), H - 1), y1c = min(max(y0 + 1, 0), H - 1);
  int x0c = min(max(x0, 0), W - 1), x1c = min(max(x0 + 1, 0), W - 1);
  const float* s = in + ((size_t)n * C + c) * H * W;
  float v = (1.f - wy) * ((1.f - wx) * s[(size_t)y0c * W + x0c] + wx * s[(size_t)y0c * W + x1c]) +
            wy * ((1.f - wx) * s[(size_t)y1c * W + x0c] + wx * s[(size_t)y1c * W + x1c]);
  out[(((size_t)n * ocstride + ocoff + c) * Ho + yo) * Wo + xo] = v;
}

// ---------------- CHW -> HWC transpose (C=16), LDS tiled ----------------
__global__ __launch_bounds__(256) void chw2hwc16_k(
    const float* __restrict__ src, float* __restrict__ dst, int HW) {
  __shared__ float t[16 * 65];
  int n = blockIdx.y;
  int p0 = blockIdx.x * 64;
  int tid = threadIdx.x;
  for (int e = tid; e < 1024; e += 256) {
    int c = e >> 6, j = e & 63;
    t[c * 65 + j] = src[((size_t)n * 16 + c) * HW + p0 + j];
  }
  __syncthreads();
  for (int e = tid; e < 1024; e += 256) {
    int j = e >> 4, c = e & 15;
    dst[((size_t)n * HW + p0 + j) * 16 + c] = t[c * 65 + j];
  }
}

// ---------------- deform weight reorder: (O,16,9) -> (9,16,O) ----------------
__global__ __launch_bounds__(256) void wreorder_k(
    const float* __restrict__ a, const float* __restrict__ b,
    const float* __restrict__ c, const float* __restrict__ d,
    float* __restrict__ out) {
  int t = blockIdx.x * 256 + threadIdx.x;
  if (t < 6912) {
    int which = t / 2304, r = t % 2304;
    int o = r % 16, kc = r / 16;
    int ci = kc % 16, k = kc / 16;
    const float* w = which == 0 ? a : (which == 1 ? b : c);
    out[t] = w[(o * 16 + ci) * 9 + k];
  } else if (t < 7200) {
    int r = t - 6912;
    int o = r % 2, kc = r / 2;
    int ci = kc % 16, k = kc / 16;
    out[t] = d[(o * 16 + ci) * 9 + k];
  }
}

// ---------------- conv weight reorder: (O,C,9) -> (C,9,O) ----------------
struct WEntry { const float* src; int cin; int cout; int dstoff; };
struct WTable { WEntry e[17]; };
__global__ __launch_bounds__(256) void wreorder_conv_k(WTable t, float* __restrict__ out) {
  WEntry en = t.e[blockIdx.y];
  int total = en.cin * en.cout * 9;
  int i = blockIdx.x * 256 + threadIdx.x;
  if (i >= total) return;
  int o = i % en.cout;
  int ck = i / en.cout;
  int k = ck % 9;
  int c = ck / 9;
  out[en.dstoff + i] = en.src[((size_t)o * en.cin + c) * 9 + k];
}

// ---------------- 3x3 conv v3: 16x16 tile, dual input, (c,k,o) weights ----------------
// LDS pitch 24: wave rows (ty 0..3) start at banks {0,24,16,8} -> 2 lanes/bank, conflict-free.
template <int L, int COUT>
__device__ __forceinline__ void conv_inner(const float* __restrict__ lds,
                                           const float* __restrict__ wc0,
                                           float* __restrict__ acc, int ty, int tx) {
#pragma unroll
  for (int c = 0; c < L; ++c) {
    const float* ld = lds + c * (18 * 24) + ty * 24 + tx;
    float v[3][3];
#pragma unroll
    for (int dy = 0; dy < 3; ++dy)
#pragma unroll
      for (int dx = 0; dx < 3; ++dx) v[dy][dx] = ld[dy * 24 + dx];
    const float* wc = wc0 + c * 9 * COUT;
#pragma unroll
    for (int k = 0; k < 9; ++k) {
#pragma unroll
      for (int o = 0; o < COUT; ++o)
        acc[o] = fmaf(v[k / 3][k % 3], wc[k * COUT + o], acc[o]);
    }
  }
}

template <int CIN0, int CIN1, int COUT>
__global__ __launch_bounds__(256) void conv3x3_v3(
    const float* __restrict__ in0, const float* __restrict__ in1,
    const float* __restrict__ wro, const float* __restrict__ bias,
    float* __restrict__ out, int H, int W, int relu) {
  constexpr int CIN = CIN0 + CIN1;
  constexpr int CH = (CIN < 8) ? CIN : 8;
  constexpr int NPASS = (CIN + CH - 1) / CH;
  constexpr int LAST = CIN - (NPASS - 1) * CH;
  __shared__ float lds[CH * 18 * 24];
  const int n = blockIdx.z;
  const int bx = blockIdx.x * 16, by = blockIdx.y * 16;
  const int tx = threadIdx.x, ty = threadIdx.y;
  const int tid = ty * 16 + tx;
  const float* i0 = in0 + (size_t)n * CIN0 * H * W;
  const float* i1 = in1 + (size_t)n * CIN1 * H * W;
  float acc[COUT];
#pragma unroll
  for (int o = 0; o < COUT; ++o) acc[o] = bias ? bias[o] : 0.f;

  for (int pass = 0; pass < NPASS; ++pass) {
    const int c0 = pass * CH;
    const int L = (pass < NPASS - 1) ? CH : LAST;
    if (pass) __syncthreads();
    for (int idx = tid; idx < L * 324; idx += 256) {
      int c = idx / 324;
      int r = idx - c * 324;
      int ly = r / 18, lx = r - ly * 18;
      int gy = by + ly - 1, gx = bx + lx - 1;
      int gc = c0 + c;
      float v = 0.f;
      if (gy >= 0 && gy < H && gx >= 0 && gx < W)
        v = (gc < CIN0) ? i0[((size_t)gc * H + gy) * W + gx]
                        : i1[((size_t)(gc - CIN0) * H + gy) * W + gx];
      lds[c * (18 * 24) + ly * 24 + lx] = v;
    }
    __syncthreads();
    const float* wc0 = wro + (size_t)c0 * 9 * COUT;
    if (pass < NPASS - 1)
      conv_inner<CH, COUT>(lds, wc0, acc, ty, tx);
    else
      conv_inner<LAST, COUT>(lds, wc0, acc, ty, tx);
  }

  const int h = by + ty, x = bx + tx;
  float* outN = out + ((size_t)n * COUT) * H * W + (size_t)h * W + x;
#pragma unroll
  for (int o = 0; o < COUT; ++o) {
    float r = acc[o];
    if (relu) r = fmaxf(r, 0.f);
    outN[(size_t)o * H * W] = r;
  }
}

// ---------------- deformable 3x3 conv v3: HWC input, (k,c,o) weights ----------------
template <int COUT, int DG>
__global__ __launch_bounds__(256) void deform_v3(
    const float* __restrict__ inHWC, const float* __restrict__ off,
    const float* __restrict__ wt, float* __restrict__ out,
    int H, int W, int relu, int ocoff, int ocstride) {
  constexpr int CIN = 16;
  constexpr int CG = CIN / DG;
  const int n = blockIdx.y;
  const int HWt = H * W;
  const int hw = blockIdx.x * 256 + threadIdx.x;
  const int h = hw / W, w = hw - h * W;
  const float* inN = inHWC + (size_t)n * HWt * CIN;
  const float* offN = off + (size_t)n * (DG * 18) * HWt + hw;
  float acc[COUT];
#pragma unroll
  for (int o = 0; o < COUT; ++o) acc[o] = 0.f;
#pragma unroll
  for (int g = 0; g < DG; ++g) {
#pragma unroll
    for (int k = 0; k < 9; ++k) {
      const int ky = k / 3 - 1, kx = k % 3 - 1;
      float oy = offN[(size_t)((g * 9 + k) * 2 + 0) * HWt];
      float ox = offN[(size_t)((g * 9 + k) * 2 + 1) * HWt];
      float py = (float)(h + ky) + oy;
      float px = (float)(w + kx) + ox;
      float y0f = floorf(py), x0f = floorf(px);
      float fy = py - y0f, fx = px - x0f;
      int y0 = (int)y0f, x0 = (int)x0f;
      bool vy0 = ((unsigned)y0 < (unsigned)H);
      bool vy1 = ((unsigned)(y0 + 1) < (unsigned)H);
      bool vx0 = ((unsigned)x0 < (unsigned)W);
      bool vx1 = ((unsigned)(x0 + 1) < (unsigned)W);
      int y0c = min(max(y0, 0), H - 1), y1c = min(max(y0 + 1, 0), H - 1);
      int x0c = min(max(x0, 0), W - 1), x1c = min(max(x0 + 1, 0), W - 1);
      float w00 = (vy0 && vx0) ? (1.f - fy) * (1.f - fx) : 0.f;
      float w01 = (vy0 && vx1) ? (1.f - fy) * fx : 0.f;
      float w10 = (vy1 && vx0) ? fy * (1.f - fx) : 0.f;
      float w11 = (vy1 && vx1) ? fy * fx : 0.f;
      const float* p00 = inN + ((size_t)y0c * W + x0c) * CIN + g * CG;
      const float* p01 = inN + ((size_t)y0c * W + x1c) * CIN + g * CG;
      const float* p10 = inN + ((size_t)y1c * W + x0c) * CIN + g * CG;
      const float* p11 = inN + ((size_t)y1c * W + x1c) * CIN + g * CG;
      const float* wk = wt + (k * CIN + g * CG) * COUT;
#pragma unroll
      for (int c4 = 0; c4 < CG / 4; ++c4) {
        float4 a00 = *(const float4*)(p00 + c4 * 4);
        float4 a01 = *(const float4*)(p01 + c4 * 4);
        float4 a10 = *(const float4*)(p10 + c4 * 4);
        float4 a11 = *(const float4*)(p11 + c4 * 4);
        float v0 = w00 * a00.x + w01 * a01.x + w10 * a10.x + w11 * a11.x;
        float v1 = w00 * a00.y + w01 * a01.y + w10 * a10.y + w11 * a11.y;
        float v2 = w00 * a00.z + w01 * a01.z + w10 * a10.z + w11 * a11.z;
        float v3 = w00 * a00.w + w01 * a01.w + w10 * a10.w + w11 * a11.w;
#pragma unroll
        for (int o = 0; o < COUT; ++o) {
          float t0 = fmaf(v0, wk[(c4 * 4 + 0) * COUT + o], acc[o]);
          t0 = fmaf(v1, wk[(c4 * 4 + 1) * COUT + o], t0);
          t0 = fmaf(v2, wk[(c4 * 4 + 2) * COUT + o], t0);
          acc[o] = fmaf(v3, wk[(c4 * 4 + 3) * COUT + o], t0);
        }
      }
    }
  }
  float* outN = out + ((size_t)n * ocstride + ocoff) * HWt + hw;
#pragma unroll
  for (int o = 0; o < COUT; ++o) {
    float r = acc[o];
    if (relu) r = fmaxf(r, 0.f);
    outN[(size_t)o * HWt] = r;
  }
}

// ---------------- host-side launch helpers ----------------
template <int C0, int C1, int CO>
static void LC(hipStream_t s, const float* a, const float* b, const float* w,
               const float* bi, float* o, int N, int H, int W, bool relu) {
  conv3x3_v3<C0, C1, CO><<<dim3(W / 16, H / 16, N), dim3(16, 16), 0, s>>>(
      a, b, w, bi, o, H, W, relu ? 1 : 0);
}

static void L_deform3(hipStream_t s, const float* inHWC, const float* off, const float* wt,
                      float* out, int N, int H, int W, int dg, int Cout, bool relu,
                      int ocoff, int ocstride) {
  dim3 grd(H * W / 256, N);
  int r = relu ? 1 : 0;
  if (Cout == 16 && dg == 1)
    deform_v3<16, 1><<<grd, 256, 0, s>>>(inHWC, off, wt, out, H, W, r, ocoff, ocstride);
  else if (Cout == 2 && dg == 2)
    deform_v3<2, 2><<<grd, 256, 0, s>>>(inHWC, off, wt, out, H, W, r, ocoff, ocstride);
}

static void L_hwc(hipStream_t s, const float* src, float* dst, int N, int HW) {
  dim3 grd(HW / 64, N);
  chw2hwc16_k<<<grd, 256, 0, s>>>(src, dst, HW);
}

static void L_pool(hipStream_t s, const float* in, float* out, int NC, int H, int W) {
  int Ho = H / 2, Wo = W / 2;
  int total = NC * Ho * Wo;
  maxpool3s2_k<<<(total + TB - 1) / TB, TB, 0, s>>>(in, out, NC, H, W, Ho, Wo);
}

static void L_up2(hipStream_t s, const float* in, float* out, int N, int C, int H, int W,
                  int ocoff, int ocstride) {
  int total = N * C * 4 * H * W;
  up2_k<<<(total + TB - 1) / TB, TB, 0, s>>>(in, out, N, C, H, W, ocoff, ocstride);
}

extern "C" void kernel_launch(void* const* d_in, const int* in_sizes, int n_in,
                              void* d_out, int out_size, void* d_ws, size_t ws_size,
                              hipStream_t stream) {
  auto F = [&](int i) { return (const float*)d_in[i]; };
  const float* ref = F(0);
  const float* unr = F(1);
  const float* few1[3] = {F(2), F(6), F(10)};
  const float* feb1[3] = {F(3), F(7), F(11)};
  const float* few2[3] = {F(4), F(8), F(12)};
  const float* feb2[3] = {F(5), F(9), F(13)};
  const float* obw[3] = {F(14), F(16), F(18)};
  const float* obb[3] = {F(15), F(17), F(19)};
  const float* ogw[3] = {F(20), F(22), F(24)};
  const float* ogb[3] = {F(21), F(23), F(25)};
  const float* dcw[3] = {F(26), F(27), F(28)};
  const float* fcw[3] = {F(29), F(31), F(33)};
  const float* fcb[3] = {F(30), F(32), F(34)};
  const float* dobw = F(35);
  const float* dobb = F(36);
  const float* dogw = F(37);
  const float* dogb = F(38);
  const float* ddcw = F(39);

  // ---- workspace layout (floats) ----
  float* ws = (float*)d_ws;
  size_t p = 0;
  auto alloc = [&](size_t nf) { float* r = ws + p; p += nf; return r; };
  const size_t SC = 9437184;  // fits (4,36,256,256), (2,16,512,512)
  float* A = alloc(SC);
  float* Bf = alloc(SC);
  float* rf[3], *uf[3], *offs[3], *feats[3];
  rf[0] = alloc((size_t)4 * 16 * 256 * 256);
  uf[0] = alloc((size_t)4 * 16 * 256 * 256);
  rf[1] = alloc((size_t)4 * 16 * 128 * 128);
  uf[1] = alloc((size_t)4 * 16 * 128 * 128);
  rf[2] = alloc((size_t)4 * 16 * 64 * 64);
  uf[2] = alloc((size_t)4 * 16 * 64 * 64);
  offs[0] = alloc((size_t)4 * 18 * 256 * 256);
  offs[1] = alloc((size_t)4 * 18 * 128 * 128);
  offs[2] = alloc((size_t)4 * 18 * 64 * 64);
  feats[0] = alloc((size_t)4 * 16 * 256 * 256);
  feats[1] = alloc((size_t)4 * 16 * 128 * 128);
  feats[2] = alloc((size_t)4 * 16 * 64 * 64);
  float* wt = alloc(7200);    // reordered deform weights (9,16,O)
  float* cw = alloc(70000);   // reordered conv weights (c,9,o)
  if (p * sizeof(float) > ws_size) return;
  const float* wt_dc[3] = {wt, wt + 2304, wt + 4608};
  const float* wt_ddc = wt + 6912;

  // ---- build conv weight reorder table ----
  WTable T;
  int nw = 0, woff = 0, maxtot = 0;
  auto addw = [&](const float* src, int cin, int cout) {
    T.e[nw].src = src; T.e[nw].cin = cin; T.e[nw].cout = cout; T.e[nw].dstoff = woff;
    int tot = cin * cout * 9;
    if (tot > maxtot) maxtot = tot;
    int start = woff;
    woff += tot;
    ++nw;
    return start;
  };
  int o_few1[3], o_few2[3], o_ob[3], o_og[3], o_fc[3], o_dob, o_dog;
  for (int i = 0; i < 3; ++i) o_few1[i] = addw(few1[i], i == 0 ? 1 : 16, 16);
  for (int i = 0; i < 3; ++i) o_few2[i] = addw(few2[i], 16, 16);
  for (int i = 0; i < 3; ++i) o_ob[i] = addw(obw[i], 32, 16);
  o_og[0] = addw(ogw[0], 34, 18);
  o_og[1] = addw(ogw[1], 34, 18);
  o_og[2] = addw(ogw[2], 16, 18);
  for (int i = 0; i < 3; ++i) o_fc[i] = addw(fcw[i], i == 2 ? 16 : 32, 16);
  o_dob = addw(dobw, 32, 16);
  o_dog = addw(dogw, 34, 36);

  wreorder_k<<<29, 256, 0, stream>>>(dcw[0], dcw[1], dcw[2], ddcw, wt);
  wreorder_conv_k<<<dim3((maxtot + 255) / 256, nw), 256, 0, stream>>>(T, cw);

  // ---- feature-extraction pyramids ----
  const float* imgs[2] = {ref, unr};
  float** pyr[2] = {rf, uf};
  for (int im = 0; im < 2; ++im) {
    for (int ch = 0; ch < 2; ++ch) {  // 512^2 level in two N=2 chunks
      const float* src = imgs[im] + (size_t)ch * 2 * 512 * 512;
      LC<1, 0, 16>(stream, src, nullptr, cw + o_few1[0], feb1[0], A, 2, 512, 512, true);
      LC<16, 0, 16>(stream, A, nullptr, cw + o_few2[0], feb2[0], Bf, 2, 512, 512, true);
      L_pool(stream, Bf, pyr[im][0] + (size_t)ch * 2 * 16 * 256 * 256, 2 * 16, 512, 512);
    }
    LC<16, 0, 16>(stream, pyr[im][0], nullptr, cw + o_few1[1], feb1[1], A, 4, 256, 256, true);
    LC<16, 0, 16>(stream, A, nullptr, cw + o_few2[1], feb2[1], Bf, 4, 256, 256, true);
    L_pool(stream, Bf, pyr[im][1], 4 * 16, 256, 256);
    LC<16, 0, 16>(stream, pyr[im][1], nullptr, cw + o_few1[2], feb1[2], A, 4, 128, 128, true);
    LC<16, 0, 16>(stream, A, nullptr, cw + o_few2[2], feb2[2], Bf, 4, 128, 128, true);
    L_pool(stream, Bf, pyr[im][2], 4 * 16, 128, 128);
  }

  // ---- coarse-to-fine alignment ----
  int Hs[3] = {256, 128, 64};
  for (int i = 2; i >= 0; --i) {
    int H = Hs[i];
    int hw = H * H;
    float* oBuf = Bf;                       // 16ch compact
    float* upo = Bf + (size_t)4 * 16 * hw;  // 18ch compact (i<2)
    float* hwcB = A;                        // HWC of uf[i]
    float* fBuf = A + (size_t)4 * 16 * hw;  // 16ch compact
    if (i == 2) {
      LC<16, 16, 16>(stream, rf[2], uf[2], cw + o_ob[2], obb[2], oBuf, 4, H, H, true);
      LC<16, 0, 18>(stream, oBuf, nullptr, cw + o_og[2], ogb[2], offs[2], 4, H, H, true);
      L_hwc(stream, uf[2], hwcB, 4, hw);
      L_deform3(stream, hwcB, offs[2], wt_dc[2], fBuf, 4, H, H, 1, 16, true, 0, 16);
      LC<16, 0, 16>(stream, fBuf, nullptr, cw + o_fc[2], fcb[2], feats[2], 4, H, H, true);
    } else {
      LC<16, 16, 16>(stream, rf[i], uf[i], cw + o_ob[i], obb[i], oBuf, 4, H, H, true);
      L_up2(stream, offs[i + 1], upo, 4, 18, H / 2, H / 2, 0, 18);
      LC<16, 18, 18>(stream, oBuf, upo, cw + o_og[i], ogb[i], offs[i], 4, H, H, true);
      L_hwc(stream, uf[i], hwcB, 4, hw);
      L_deform3(stream, hwcB, offs[i], wt_dc[i], fBuf, 4, H, H, 1, 16, true, 0, 16);
      L_up2(stream, feats[i + 1], uf[i], 4, 16, H / 2, H / 2, 0, 16);  // uf[i] is dead
      LC<16, 16, 16>(stream, fBuf, uf[i], cw + o_fc[i], fcb[i], feats[i], 4, H, H, true);
    }
  }

  // ---- final offset head + deform (dg=2) ----
  const int hw0 = 256 * 256;
  float* doBuf = Bf;  // 16ch
  LC<16, 16, 16>(stream, rf[0], feats[0], cw + o_dob, dobb, doBuf, 4, 256, 256, false);
  LC<16, 18, 36>(stream, doBuf, offs[0], cw + o_dog, dogb, A, 4, 256, 256, false);  // 36ch -> A
  float* fHwc = Bf + (size_t)4 * 16 * hw0;  // doBuf consumed
  L_hwc(stream, feats[0], fHwc, 4, hw0);
  L_deform3(stream, fHwc, A, wt_ddc, (float*)d_out, 4, 256, 256, 2, 2, false, 0, 2);
}

// Round 7
// 1452.952 us; speedup vs baseline: 1.7850x; 1.0454x over previous
//
#include <hip/hip_runtime.h>
#include <math.h>

#define TB 256

// ---------------- maxpool 3x3 stride2 pad1 ----------------
__global__ __launch_bounds__(256) void maxpool3s2_k(
    const float* __restrict__ in, float* __restrict__ out,
    int NC, int H, int W, int Ho, int Wo) {
  int idx = blockIdx.x * TB + threadIdx.x;
  int total = NC * Ho * Wo;
  if (idx >= total) return;
  int wo = idx % Wo;
  int t = idx / Wo;
  int ho = t % Ho;
  int nc = t / Ho;
  const float* src = in + (size_t)nc * H * W;
  int y0 = 2 * ho - 1, x0 = 2 * wo - 1;
  float m = -INFINITY;
  for (int dy = 0; dy < 3; ++dy) {
    int y = y0 + dy;
    if (y < 0 || y >= H) continue;
    for (int dx = 0; dx < 3; ++dx) {
      int x = x0 + dx;
      if (x < 0 || x >= W) continue;
      m = fmaxf(m, src[(size_t)y * W + x]);
    }
  }
  out[idx] = m;
}

// ---------------- bilinear x2 upsample (jax.image.resize, half-pixel) ----------------
__global__ __launch_bounds__(256) void up2_k(
    const float* __restrict__ in, float* __restrict__ out,
    int N, int C, int H, int W, int ocoff, int ocstride) {
  int Ho = 2 * H, Wo = 2 * W;
  int total = N * C * Ho * Wo;
  int idx = blockIdx.x * TB + threadIdx.x;
  if (idx >= total) return;
  int xo = idx % Wo;
  int t = idx / Wo;
  int yo = t % Ho;
  t /= Ho;
  int c = t % C;
  int n = t / C;
  float sy = 0.5f * yo - 0.25f;
  float sx = 0.5f * xo - 0.25f;
  float y0f = floorf(sy), x0f = floorf(sx);
  float wy = sy - y0f, wx = sx - x0f;
  int y0 = (int)y0f, x0 = (int)x0f;
  int y0c = min(max(y0, 0), H - 1), y1c = min(max(y0 + 1, 0), H - 1);
  int x0c = min(max(x0, 0), W - 1), x1c = min(max(x0 + 1, 0), W - 1);
  const float* s = in + ((size_t)n * C + c) * H * W;
  float v = (1.f - wy) * ((1.f - wx) * s[(size_t)y0c * W + x0c] + wx * s[(size_t)y0c * W + x1c]) +
            wy * ((1.f - wx) * s[(size_t)y1c * W + x0c] + wx * s[(size_t)y1c * W + x1c]);
  out[(((size_t)n * ocstride + ocoff + c) * Ho + yo) * Wo + xo] = v;
}

// ---------------- CHW -> HWC transpose (C=16), LDS tiled ----------------
__global__ __launch_bounds__(256) void chw2hwc16_k(
    const float* __restrict__ src, float* __restrict__ dst, int HW) {
  __shared__ float t[16 * 65];
  int n = blockIdx.y;
  int p0 = blockIdx.x * 64;
  int tid = threadIdx.x;
  for (int e = tid; e < 1024; e += 256) {
    int c = e >> 6, j = e & 63;
    t[c * 65 + j] = src[((size_t)n * 16 + c) * HW + p0 + j];
  }
  __syncthreads();
  for (int e = tid; e < 1024; e += 256) {
    int j = e >> 4, c = e & 15;
    dst[((size_t)n * HW + p0 + j) * 16 + c] = t[c * 65 + j];
  }
}

// ---------------- deform weight reorder: (O,16,9) -> (9,16,O) ----------------
__global__ __launch_bounds__(256) void wreorder_k(
    const float* __restrict__ a, const float* __restrict__ b,
    const float* __restrict__ c, const float* __restrict__ d,
    float* __restrict__ out) {
  int t = blockIdx.x * 256 + threadIdx.x;
  if (t < 6912) {
    int which = t / 2304, r = t % 2304;
    int o = r % 16, kc = r / 16;
    int ci = kc % 16, k = kc / 16;
    const float* w = which == 0 ? a : (which == 1 ? b : c);
    out[t] = w[(o * 16 + ci) * 9 + k];
  } else if (t < 7200) {
    int r = t - 6912;
    int o = r % 2, kc = r / 2;
    int ci = kc % 16, k = kc / 16;
    out[t] = d[(o * 16 + ci) * 9 + k];
  }
}

// ---------------- conv weight reorder: (O,C,9) -> (C,9,O) ----------------
struct WEntry { const float* src; int cin; int cout; int dstoff; };
struct WTable { WEntry e[20]; };  // 18 used
__global__ __launch_bounds__(256) void wreorder_conv_k(WTable t, float* __restrict__ out) {
  WEntry en = t.e[blockIdx.y];
  int total = en.cin * en.cout * 9;
  int i = blockIdx.x * 256 + threadIdx.x;
  if (i >= total) return;
  int o = i % en.cout;
  int ck = i / en.cout;
  int k = ck % 9;
  int c = ck / 9;
  out[en.dstoff + i] = en.src[((size_t)o * en.cin + c) * 9 + k];
}

// ---------------- 3x3 conv v3: 16x16 tile, dual input, (c,k,o) weights ----------------
// (R4's kernel — passed full harness — extended with ocoff/ocstride epilogue.)
// LDS pitch 24: wave rows (ty 0..3) start at banks {0,24,16,8} -> 2 lanes/bank, conflict-free.
template <int L, int COUT>
__device__ __forceinline__ void conv_inner(const float* __restrict__ lds,
                                           const float* __restrict__ wc0,
                                           float* __restrict__ acc, int ty, int tx) {
#pragma unroll
  for (int c = 0; c < L; ++c) {
    const float* ld = lds + c * (18 * 24) + ty * 24 + tx;
    float v[3][3];
#pragma unroll
    for (int dy = 0; dy < 3; ++dy)
#pragma unroll
      for (int dx = 0; dx < 3; ++dx) v[dy][dx] = ld[dy * 24 + dx];
    const float* wc = wc0 + c * 9 * COUT;
#pragma unroll
    for (int k = 0; k < 9; ++k) {
#pragma unroll
      for (int o = 0; o < COUT; ++o)
        acc[o] = fmaf(v[k / 3][k % 3], wc[k * COUT + o], acc[o]);
    }
  }
}

template <int CIN0, int CIN1, int COUT>
__global__ __launch_bounds__(256) void conv3x3_v3(
    const float* __restrict__ in0, const float* __restrict__ in1,
    const float* __restrict__ wro, const float* __restrict__ bias,
    float* __restrict__ out, int H, int W, int relu, int ocoff, int ocstride) {
  constexpr int CIN = CIN0 + CIN1;
  constexpr int CH = (CIN < 8) ? CIN : 8;
  constexpr int NPASS = (CIN + CH - 1) / CH;
  constexpr int LAST = CIN - (NPASS - 1) * CH;
  __shared__ float lds[CH * 18 * 24];
  const int n = blockIdx.z;
  const int bx = blockIdx.x * 16, by = blockIdx.y * 16;
  const int tx = threadIdx.x, ty = threadIdx.y;
  const int tid = ty * 16 + tx;
  const float* i0 = in0 + (size_t)n * CIN0 * H * W;
  const float* i1 = in1 + (size_t)n * CIN1 * H * W;
  float acc[COUT];
#pragma unroll
  for (int o = 0; o < COUT; ++o) acc[o] = bias ? bias[o] : 0.f;

  for (int pass = 0; pass < NPASS; ++pass) {
    const int c0 = pass * CH;
    const int L = (pass < NPASS - 1) ? CH : LAST;
    if (pass) __syncthreads();
    for (int idx = tid; idx < L * 324; idx += 256) {
      int c = idx / 324;
      int r = idx - c * 324;
      int ly = r / 18, lx = r - ly * 18;
      int gy = by + ly - 1, gx = bx + lx - 1;
      int gc = c0 + c;
      float v = 0.f;
      if (gy >= 0 && gy < H && gx >= 0 && gx < W)
        v = (gc < CIN0) ? i0[((size_t)gc * H + gy) * W + gx]
                        : i1[((size_t)(gc - CIN0) * H + gy) * W + gx];
      lds[c * (18 * 24) + ly * 24 + lx] = v;
    }
    __syncthreads();
    const float* wc0 = wro + (size_t)c0 * 9 * COUT;
    if (pass < NPASS - 1)
      conv_inner<CH, COUT>(lds, wc0, acc, ty, tx);
    else
      conv_inner<LAST, COUT>(lds, wc0, acc, ty, tx);
  }

  const int h = by + ty, x = bx + tx;
#pragma unroll
  for (int o = 0; o < COUT; ++o) {
    float r = acc[o];
    if (relu) r = fmaxf(r, 0.f);
    out[(((size_t)n * ocstride + ocoff + o) * H + h) * W + x] = r;
  }
}

// ---------------- deformable 3x3 conv v3: HWC input, (k,c,o) weights ----------------
template <int COUT, int DG>
__global__ __launch_bounds__(256) void deform_v3(
    const float* __restrict__ inHWC, const float* __restrict__ off,
    const float* __restrict__ wt, float* __restrict__ out,
    int H, int W, int relu, int ocoff, int ocstride) {
  constexpr int CIN = 16;
  constexpr int CG = CIN / DG;
  const int n = blockIdx.y;
  const int HWt = H * W;
  const int hw = blockIdx.x * 256 + threadIdx.x;
  const int h = hw / W, w = hw - h * W;
  const float* inN = inHWC + (size_t)n * HWt * CIN;
  const float* offN = off + (size_t)n * (DG * 18) * HWt + hw;
  float acc[COUT];
#pragma unroll
  for (int o = 0; o < COUT; ++o) acc[o] = 0.f;
#pragma unroll
  for (int g = 0; g < DG; ++g) {
#pragma unroll
    for (int k = 0; k < 9; ++k) {
      const int ky = k / 3 - 1, kx = k % 3 - 1;
      float oy = offN[(size_t)((g * 9 + k) * 2 + 0) * HWt];
      float ox = offN[(size_t)((g * 9 + k) * 2 + 1) * HWt];
      float py = (float)(h + ky) + oy;
      float px = (float)(w + kx) + ox;
      float y0f = floorf(py), x0f = floorf(px);
      float fy = py - y0f, fx = px - x0f;
      int y0 = (int)y0f, x0 = (int)x0f;
      bool vy0 = ((unsigned)y0 < (unsigned)H);
      bool vy1 = ((unsigned)(y0 + 1) < (unsigned)H);
      bool vx0 = ((unsigned)x0 < (unsigned)W);
      bool vx1 = ((unsigned)(x0 + 1) < (unsigned)W);
      int y0c = min(max(y0, 0), H - 1), y1c = min(max(y0 + 1, 0), H - 1);
      int x0c = min(max(x0, 0), W - 1), x1c = min(max(x0 + 1, 0), W - 1);
      float w00 = (vy0 && vx0) ? (1.f - fy) * (1.f - fx) : 0.f;
      float w01 = (vy0 && vx1) ? (1.f - fy) * fx : 0.f;
      float w10 = (vy1 && vx0) ? fy * (1.f - fx) : 0.f;
      float w11 = (vy1 && vx1) ? fy * fx : 0.f;
      const float* p00 = inN + ((size_t)y0c * W + x0c) * CIN + g * CG;
      const float* p01 = inN + ((size_t)y0c * W + x1c) * CIN + g * CG;
      const float* p10 = inN + ((size_t)y1c * W + x0c) * CIN + g * CG;
      const float* p11 = inN + ((size_t)y1c * W + x1c) * CIN + g * CG;
      const float* wk = wt + (k * CIN + g * CG) * COUT;
#pragma unroll
      for (int c4 = 0; c4 < CG / 4; ++c4) {
        float4 a00 = *(const float4*)(p00 + c4 * 4);
        float4 a01 = *(const float4*)(p01 + c4 * 4);
        float4 a10 = *(const float4*)(p10 + c4 * 4);
        float4 a11 = *(const float4*)(p11 + c4 * 4);
        float v0 = w00 * a00.x + w01 * a01.x + w10 * a10.x + w11 * a11.x;
        float v1 = w00 * a00.y + w01 * a01.y + w10 * a10.y + w11 * a11.y;
        float v2 = w00 * a00.z + w01 * a01.z + w10 * a10.z + w11 * a11.z;
        float v3 = w00 * a00.w + w01 * a01.w + w10 * a10.w + w11 * a11.w;
#pragma unroll
        for (int o = 0; o < COUT; ++o) {
          float t0 = fmaf(v0, wk[(c4 * 4 + 0) * COUT + o], acc[o]);
          t0 = fmaf(v1, wk[(c4 * 4 + 1) * COUT + o], t0);
          t0 = fmaf(v2, wk[(c4 * 4 + 2) * COUT + o], t0);
          acc[o] = fmaf(v3, wk[(c4 * 4 + 3) * COUT + o], t0);
        }
      }
    }
  }
  float* outN = out + ((size_t)n * ocstride + ocoff) * HWt + hw;
#pragma unroll
  for (int o = 0; o < COUT; ++o) {
    float r = acc[o];
    if (relu) r = fmaxf(r, 0.f);
    outN[(size_t)o * HWt] = r;
  }
}

// ---------------- host-side launch helpers ----------------
template <int C0, int C1, int CO>
static void LC(hipStream_t s, const float* a, const float* b, const float* w,
               const float* bi, float* o, int N, int H, int W, bool relu,
               int ocoff, int ocstride) {
  conv3x3_v3<C0, C1, CO><<<dim3(W / 16, H / 16, N), dim3(16, 16), 0, s>>>(
      a, b, w, bi, o, H, W, relu ? 1 : 0, ocoff, ocstride);
}

static void L_deform3(hipStream_t s, const float* inHWC, const float* off, const float* wt,
                      float* out, int N, int H, int W, int dg, int Cout, bool relu,
                      int ocoff, int ocstride) {
  dim3 grd(H * W / 256, N);
  int r = relu ? 1 : 0;
  if (Cout == 16 && dg == 1)
    deform_v3<16, 1><<<grd, 256, 0, s>>>(inHWC, off, wt, out, H, W, r, ocoff, ocstride);
  else if (Cout == 2 && dg == 2)
    deform_v3<2, 2><<<grd, 256, 0, s>>>(inHWC, off, wt, out, H, W, r, ocoff, ocstride);
}

static void L_hwc(hipStream_t s, const float* src, float* dst, int N, int HW) {
  dim3 grd(HW / 64, N);
  chw2hwc16_k<<<grd, 256, 0, s>>>(src, dst, HW);
}

static void L_pool(hipStream_t s, const float* in, float* out, int NC, int H, int W) {
  int Ho = H / 2, Wo = W / 2;
  int total = NC * Ho * Wo;
  maxpool3s2_k<<<(total + TB - 1) / TB, TB, 0, s>>>(in, out, NC, H, W, Ho, Wo);
}

static void L_up2(hipStream_t s, const float* in, float* out, int N, int C, int H, int W,
                  int ocoff, int ocstride) {
  int total = N * C * 4 * H * W;
  up2_k<<<(total + TB - 1) / TB, TB, 0, s>>>(in, out, N, C, H, W, ocoff, ocstride);
}

extern "C" void kernel_launch(void* const* d_in, const int* in_sizes, int n_in,
                              void* d_out, int out_size, void* d_ws, size_t ws_size,
                              hipStream_t stream) {
  auto F = [&](int i) { return (const float*)d_in[i]; };
  const float* ref = F(0);
  const float* unr = F(1);
  const float* few1[3] = {F(2), F(6), F(10)};
  const float* feb1[3] = {F(3), F(7), F(11)};
  const float* few2[3] = {F(4), F(8), F(12)};
  const float* feb2[3] = {F(5), F(9), F(13)};
  const float* obw[3] = {F(14), F(16), F(18)};
  const float* obb[3] = {F(15), F(17), F(19)};
  const float* ogw[3] = {F(20), F(22), F(24)};
  const float* ogb[3] = {F(21), F(23), F(25)};
  const float* dcw[3] = {F(26), F(27), F(28)};
  const float* fcw[3] = {F(29), F(31), F(33)};
  const float* fcb[3] = {F(30), F(32), F(34)};
  const float* dobw = F(35);
  const float* dobb = F(36);
  const float* dogw = F(37);
  const float* dogb = F(38);
  const float* ddcw = F(39);

  // ---- workspace layout (floats) ----
  float* ws = (float*)d_ws;
  size_t p = 0;
  auto alloc = [&](size_t nf) { float* r = ws + p; p += nf; return r; };
  const size_t SC = 9437184;  // fits (4,36,256,256), (2,16,512,512)
  float* A = alloc(SC);
  float* Bf = alloc(SC);
  float* rf[3], *uf[3], *offs[3], *feats[3];
  rf[0] = alloc((size_t)4 * 16 * 256 * 256);
  uf[0] = alloc((size_t)4 * 16 * 256 * 256);
  rf[1] = alloc((size_t)4 * 16 * 128 * 128);
  uf[1] = alloc((size_t)4 * 16 * 128 * 128);
  rf[2] = alloc((size_t)4 * 16 * 64 * 64);
  uf[2] = alloc((size_t)4 * 16 * 64 * 64);
  offs[0] = alloc((size_t)4 * 18 * 256 * 256);
  offs[1] = alloc((size_t)4 * 18 * 128 * 128);
  offs[2] = alloc((size_t)4 * 18 * 64 * 64);
  feats[0] = alloc((size_t)4 * 16 * 256 * 256);
  feats[1] = alloc((size_t)4 * 16 * 128 * 128);
  feats[2] = alloc((size_t)4 * 16 * 64 * 64);
  float* wt = alloc(7200);    // reordered deform weights (9,16,O)
  float* cw = alloc(70000);   // reordered conv weights (c,9,o)
  if (p * sizeof(float) > ws_size) return;
  const float* wt_dc[3] = {wt, wt + 2304, wt + 4608};
  const float* wt_ddc = wt + 6912;

  // ---- build conv weight reorder table (dog split into two 18-out halves) ----
  WTable T;
  int nw = 0, woff = 0, maxtot = 0;
  auto addw = [&](const float* src, int cin, int cout) {
    T.e[nw].src = src; T.e[nw].cin = cin; T.e[nw].cout = cout; T.e[nw].dstoff = woff;
    int tot = cin * cout * 9;
    if (tot > maxtot) maxtot = tot;
    int start = woff;
    woff += tot;
    ++nw;
    return start;
  };
  int o_few1[3], o_few2[3], o_ob[3], o_og[3], o_fc[3], o_dob, o_dog0, o_dog1;
  for (int i = 0; i < 3; ++i) o_few1[i] = addw(few1[i], i == 0 ? 1 : 16, 16);
  for (int i = 0; i < 3; ++i) o_few2[i] = addw(few2[i], 16, 16);
  for (int i = 0; i < 3; ++i) o_ob[i] = addw(obw[i], 32, 16);
  o_og[0] = addw(ogw[0], 34, 18);
  o_og[1] = addw(ogw[1], 34, 18);
  o_og[2] = addw(ogw[2], 16, 18);
  for (int i = 0; i < 3; ++i) o_fc[i] = addw(fcw[i], i == 2 ? 16 : 32, 16);
  o_dob = addw(dobw, 32, 16);
  o_dog0 = addw(dogw, 34, 18);
  o_dog1 = addw(dogw + (size_t)18 * 34 * 9, 34, 18);

  wreorder_k<<<29, 256, 0, stream>>>(dcw[0], dcw[1], dcw[2], ddcw, wt);
  wreorder_conv_k<<<dim3((maxtot + 255) / 256, nw), 256, 0, stream>>>(T, cw);

  // ---- feature-extraction pyramids ----
  const float* imgs[2] = {ref, unr};
  float** pyr[2] = {rf, uf};
  for (int im = 0; im < 2; ++im) {
    for (int ch = 0; ch < 2; ++ch) {  // 512^2 level in two N=2 chunks
      const float* src = imgs[im] + (size_t)ch * 2 * 512 * 512;
      LC<1, 0, 16>(stream, src, nullptr, cw + o_few1[0], feb1[0], A, 2, 512, 512, true, 0, 16);
      LC<16, 0, 16>(stream, A, nullptr, cw + o_few2[0], feb2[0], Bf, 2, 512, 512, true, 0, 16);
      L_pool(stream, Bf, pyr[im][0] + (size_t)ch * 2 * 16 * 256 * 256, 2 * 16, 512, 512);
    }
    LC<16, 0, 16>(stream, pyr[im][0], nullptr, cw + o_few1[1], feb1[1], A, 4, 256, 256, true, 0, 16);
    LC<16, 0, 16>(stream, A, nullptr, cw + o_few2[1], feb2[1], Bf, 4, 256, 256, true, 0, 16);
    L_pool(stream, Bf, pyr[im][1], 4 * 16, 256, 256);
    LC<16, 0, 16>(stream, pyr[im][1], nullptr, cw + o_few1[2], feb1[2], A, 4, 128, 128, true, 0, 16);
    LC<16, 0, 16>(stream, A, nullptr, cw + o_few2[2], feb2[2], Bf, 4, 128, 128, true, 0, 16);
    L_pool(stream, Bf, pyr[im][2], 4 * 16, 128, 128);
  }

  // ---- coarse-to-fine alignment ----
  int Hs[3] = {256, 128, 64};
  for (int i = 2; i >= 0; --i) {
    int H = Hs[i];
    int hw = H * H;
    float* oBuf = Bf;                       // 16ch compact
    float* upo = Bf + (size_t)4 * 16 * hw;  // 18ch compact (i<2)
    float* hwcB = A;                        // HWC of uf[i]
    float* fBuf = A + (size_t)4 * 16 * hw;  // 16ch compact
    if (i == 2) {
      LC<16, 16, 16>(stream, rf[2], uf[2], cw + o_ob[2], obb[2], oBuf, 4, H, H, true, 0, 16);
      LC<16, 0, 18>(stream, oBuf, nullptr, cw + o_og[2], ogb[2], offs[2], 4, H, H, true, 0, 18);
      L_hwc(stream, uf[2], hwcB, 4, hw);
      L_deform3(stream, hwcB, offs[2], wt_dc[2], fBuf, 4, H, H, 1, 16, true, 0, 16);
      LC<16, 0, 16>(stream, fBuf, nullptr, cw + o_fc[2], fcb[2], feats[2], 4, H, H, true, 0, 16);
    } else {
      LC<16, 16, 16>(stream, rf[i], uf[i], cw + o_ob[i], obb[i], oBuf, 4, H, H, true, 0, 16);
      L_up2(stream, offs[i + 1], upo, 4, 18, H / 2, H / 2, 0, 18);
      LC<16, 18, 18>(stream, oBuf, upo, cw + o_og[i], ogb[i], offs[i], 4, H, H, true, 0, 18);
      L_hwc(stream, uf[i], hwcB, 4, hw);
      L_deform3(stream, hwcB, offs[i], wt_dc[i], fBuf, 4, H, H, 1, 16, true, 0, 16);
      L_up2(stream, feats[i + 1], uf[i], 4, 16, H / 2, H / 2, 0, 16);  // uf[i] is dead
      LC<16, 16, 16>(stream, fBuf, uf[i], cw + o_fc[i], fcb[i], feats[i], 4, H, H, true, 0, 16);
    }
  }

  // ---- final offset head + deform (dg=2) ----
  const int hw0 = 256 * 256;
  float* doBuf = Bf;  // 16ch
  LC<16, 16, 16>(stream, rf[0], feats[0], cw + o_dob, dobb, doBuf, 4, 256, 256, false, 0, 16);
  // dog 34->36 as two 18-out halves into 36-stride buffer A
  LC<16, 18, 18>(stream, doBuf, offs[0], cw + o_dog0, dogb, A, 4, 256, 256, false, 0, 36);
  LC<16, 18, 18>(stream, doBuf, offs[0], cw + o_dog1, dogb + 18, A, 4, 256, 256, false, 18, 36);
  float* fHwc = Bf + (size_t)4 * 16 * hw0;  // doBuf consumed
  L_hwc(stream, feats[0], fHwc, 4, hw0);
  L_deform3(stream, fHwc, A, wt_ddc, (float*)d_out, 4, 256, 256, 2, 2, false, 0, 2);
}